// Round 11
// baseline (902.188 us; speedup 1.0000x reference)
//
#include <hip/hip_runtime.h>
#include <hip/hip_fp16.h>
#include <math.h>

// ---------------------------------------------------------------------------
// NetGlobGATFix. R11: tail optimization round.
//   - attn_kernel: pass1 stores e to fp32 scratch (coalesced); pass2 reads it
//     sequentially (no 2nd random gather). Scratch aliases P (free at attn).
//   - esed_kernel: o-pair per thread, float2 wesed loads (half the hin reads).
//   - reduce_ep: float4 vectorized.
//   - CNN (padded 66x66, unrolled) + gemm_mr split-K MFMA unchanged from R10.
// ---------------------------------------------------------------------------

#define DEVFN static __device__ __forceinline__

typedef __attribute__((ext_vector_type(8))) short short8;
typedef __attribute__((ext_vector_type(4))) float f32x4;

DEVFN float selu_f(float v) {
    const float scale = 1.0507009873554805f;
    const float alpha = 1.6732632423543772f;
    return v > 0.f ? scale * v : scale * alpha * (expf(v) - 1.f);
}

DEVFN float lrelu02(float v) { return v > 0.f ? v : 0.2f * v; }

// truncation split: hi = trunc_bf16(a); lo = trunc_bf16(a - hi)
DEVFN void split_bf16(float a, unsigned short& hi, unsigned short& lo) {
    unsigned u = __float_as_uint(a);
    hi = (unsigned short)(u >> 16);
    float hf = __uint_as_float(u & 0xFFFF0000u);
    float l = a - hf;
    lo = (unsigned short)(__float_as_uint(l) >> 16);
}

// ---------------- CNN (padded 66x66 layout) ----------------
#define PST 66
#define PSZ (66 * 66)

__global__ void pad_input(const float* __restrict__ cf, float* __restrict__ out) {
    int t = blockIdx.x * blockDim.x + threadIdx.x;
    if (t >= 4 * 4096) return;
    int c = t >> 12, pix = t & 4095;
    int y = pix >> 6, x = pix & 63;
    out[c * PSZ + (y + 1) * PST + (x + 1)] = cf[t];
}

template <int CIN>
__global__ __launch_bounds__(256) void conv3x3_pad(const float* __restrict__ in,
                                                   const float* __restrict__ w,
                                                   const float* __restrict__ b,
                                                   float* __restrict__ out) {
    int x  = threadIdx.x & 63;
    int yg = threadIdx.x >> 6;
    int y0 = blockIdx.x * 16 + yg * 4;
    int co = blockIdx.y;
    float bv = b[co];
    float acc[4] = {bv, bv, bv, bv};
    const float* wp = w + (size_t)co * CIN * 9;
#pragma unroll 4
    for (int ci = 0; ci < CIN; ++ci) {
        const float* ip = in + ci * PSZ + y0 * PST + x;
        float wr[9];
#pragma unroll
        for (int j = 0; j < 9; ++j) wr[j] = wp[ci * 9 + j];
        float r[6][3];
#pragma unroll
        for (int rr = 0; rr < 6; ++rr) {
            r[rr][0] = ip[rr * PST + 0];
            r[rr][1] = ip[rr * PST + 1];
            r[rr][2] = ip[rr * PST + 2];
        }
#pragma unroll
        for (int v = 0; v < 4; ++v)
#pragma unroll
            for (int ky = 0; ky < 3; ++ky)
#pragma unroll
                for (int kx = 0; kx < 3; ++kx)
                    acc[v] += wr[ky * 3 + kx] * r[v + ky][kx];
    }
#pragma unroll
    for (int v = 0; v < 4; ++v)
        out[(size_t)co * PSZ + (y0 + v + 1) * PST + (x + 1)] = selu_f(acc[v]);
}

__global__ void avgpool_c(const float* __restrict__ in, float* __restrict__ gfeat) {
    int c = blockIdx.x;            // 24 blocks
    int t = threadIdx.x;           // 256 threads
    float s = 0.f;
    for (int i = t; i < 4096; i += 256) {
        int y = i >> 6, x = i & 63;
        s += in[c * PSZ + (y + 1) * PST + (x + 1)];
    }
#pragma unroll
    for (int off = 32; off >= 1; off >>= 1) s += __shfl_xor(s, off);
    __shared__ float red[4];
    int wave = t >> 6, lane = t & 63;
    if (lane == 0) red[wave] = s;
    __syncthreads();
    if (t == 0) gfeat[c] = (red[0] + red[1] + red[2] + red[3]) * (1.f / 4096.f);
}

// ---------------- node feature init (padded to 48 ch, fp16) + masks ---------
__global__ void build_h0(const float* __restrict__ x, const float* __restrict__ gfeat,
                         __half* __restrict__ h0f, unsigned* __restrict__ masks, int N) {
    int n = blockIdx.x * blockDim.x + threadIdx.x;
    if (n >= N) return;
    float x0 = x[n * 10 + 0], x1 = x[n * 10 + 1];
    unsigned mk = (x0 == 1.f ? 1u : 0u) | (x0 == 0.f ? 2u : 0u) |
                  (x1 == 0.f ? 4u : 0u) | (x1 == 1.f ? 8u : 0u);
    masks[n] = mk;
    __half* hq = h0f + (size_t)n * 48;
#pragma unroll
    for (int j = 0; j < 48; ++j) {
        float v = (j < 24) ? gfeat[j] : (j < 34 ? x[n * 10 + (j - 24)] : 0.f);
        hq[j] = __float2half(v);
    }
}

// ---------------- CSR build ----------------
__global__ void count_dst(const int* __restrict__ ei, int* __restrict__ cnt, int E, int N) {
    int t = blockIdx.x * blockDim.x + threadIdx.x;
    if (t >= E + N) return;
    int dst = (t < E) ? ei[E + t] : (t - E);
    atomicAdd(&cnt[dst], 1);
}

__global__ void exscan_single(const int* __restrict__ cnt, int* __restrict__ indptr, int n) {
    __shared__ int sdata[256];
    __shared__ int run_s;
    int tid = threadIdx.x;
    if (tid == 0) { run_s = 0; indptr[0] = 0; }
    __syncthreads();
    for (int base = 0; base < n; base += 256) {
        int i = base + tid;
        int v = (i < n) ? cnt[i] : 0;
        sdata[tid] = v;
        __syncthreads();
        for (int off = 1; off < 256; off <<= 1) {
            int tmp = (tid >= off) ? sdata[tid - off] : 0;
            __syncthreads();
            sdata[tid] += tmp;
            __syncthreads();
        }
        if (i < n) indptr[i + 1] = run_s + sdata[tid];
        __syncthreads();
        if (tid == 0) run_s += sdata[255];
        __syncthreads();
    }
}

__global__ void copy_int(const int* __restrict__ a, int* __restrict__ b, int n) {
    int t = blockIdx.x * blockDim.x + threadIdx.x;
    if (t < n) b[t] = a[t];
}

__global__ void scatter_edges(const int* __restrict__ ei, int* __restrict__ cursor,
                              int* __restrict__ col, int E, int N) {
    int t = blockIdx.x * blockDim.x + threadIdx.x;
    if (t >= E + N) return;
    int src, dst;
    if (t < E) { src = ei[t]; dst = ei[E + t]; }
    else       { src = dst = t - E; }
    int pos = atomicAdd(&cursor[dst], 1);
    col[pos] = src;
}

// ---------------- weight prep ----------------------------------------------
__global__ void build_wesed(const float* __restrict__ W, const float* __restrict__ as,
                            const float* __restrict__ ad, float* __restrict__ wesed,
                            int K, int Kp, int H, int C) {
    int H2 = 2 * H;
    int t = blockIdx.x * blockDim.x + threadIdx.x;
    if (t >= Kp * H2) return;
    int k = t / H2, o = t - k * H2;
    float s = 0.f;
    if (k < K) {
        int h = (o < H) ? o : o - H;
        const float* av = ((o < H) ? as : ad) + h * C;
        const float* wp = W + (size_t)k * (H * C) + h * C;
        for (int c = 0; c < C; ++c) s += wp[c] * av[c];
    }
    wesed[t] = s;
}

// Bt_hi/Bt_lo[m * KA + (h*Kp + k)] = split_bf16(W[k, h*C+m]), 0 pad for k>=K
__global__ void build_wtb(const float* __restrict__ W, unsigned short* __restrict__ bhi,
                          unsigned short* __restrict__ blo, int K, int Kp, int H, int C) {
    int KA = H * Kp;
    int t = blockIdx.x * blockDim.x + threadIdx.x;
    if (t >= C * KA) return;
    int ka = t % KA;
    int m  = t / KA;
    int h = ka / Kp, k = ka - h * Kp;
    float v = (k < K) ? W[(size_t)k * (H * C) + h * C + m] : 0.f;
    unsigned short hi, lo;
    split_bf16(v, hi, lo);
    bhi[t] = hi;
    blo[t] = lo;
}

// wstack[(h*Kp+k)*C + c] = W[k, h*C+c] (fp32; final layer C=2)
__global__ void build_wstack(const float* __restrict__ W, float* __restrict__ ws,
                             int K, int Kp, int H, int C) {
    int t = blockIdx.x * blockDim.x + threadIdx.x;
    if (t >= H * Kp * C) return;
    int c = t % C;
    int r = t / C;
    int h = r / Kp, k = r - h * Kp;
    ws[t] = (k < K) ? W[(size_t)k * (H * C) + h * C + c] : 0.f;
}

// ---- es/ed: esed[n, o..o+1] = hin16[n,:] @ wesed[:, o..o+1] (o-pairs) ------
__global__ void esed_kernel(const __half* __restrict__ hin, const float* __restrict__ wesed,
                            float* __restrict__ esed, int N, int Kp, int H2) {
    int t = blockIdx.x * blockDim.x + threadIdx.x;
    int HP = H2 / 2;
    if (t >= N * HP) return;
    int n = t / HP, op = (t - n * HP) * 2;
    const __half2* hp = (const __half2*)(hin + (size_t)n * Kp);
    float s0 = 0.f, s1 = 0.f;
    for (int k2 = 0; k2 < Kp / 2; ++k2) {
        float2 f = __half22float2(hp[k2]);
        float2 w0 = *(const float2*)(wesed + (2 * k2) * H2 + op);
        float2 w1 = *(const float2*)(wesed + (2 * k2 + 1) * H2 + op);
        s0 += f.x * w0.x + f.y * w1.x;
        s1 += f.x * w0.y + f.y * w1.y;
    }
    esed[n * H2 + op]     = s0;
    esed[n * H2 + op + 1] = s1;
}

// ---------------- attention: gather-once max pass + scratch replay ----------
// pass1: e = lrelu(es[src]+ed) gathered once, stored fp32 to escr (coalesced).
// pass2: sequential escr read -> exp -> palpha fp16, z.
__global__ void attn_kernel(const float* __restrict__ esed,
                            const int* __restrict__ indptr, const int* __restrict__ col,
                            float* __restrict__ escr, __half* __restrict__ palpha,
                            float* __restrict__ zinv, int N, int H) {
    int t = blockIdx.x * blockDim.x + threadIdx.x;
    if (t >= N * H) return;
    int n = t / H, h = t - n * H;
    int H2 = 2 * H;
    float edv = esed[n * H2 + H + h];
    int beg = indptr[n], end = indptr[n + 1];
    float mv = -3.4e38f;
    for (int i = beg; i < end; ++i) {
        float e = lrelu02(esed[col[i] * H2 + h] + edv);
        escr[(size_t)i * H + h] = e;
        mv = fmaxf(mv, e);
    }
    float z = 0.f;
    for (int i = beg; i < end; ++i) {
        float e = escr[(size_t)i * H + h];
        __half ph = __float2half(expf(e - mv));
        palpha[(size_t)i * H + h] = ph;
        z += __half2float(ph);
    }
    zinv[t] = (1.f / H) / (z + 1e-16f);
}

// ---------------- gather: g[n, h*KP+k] = zinv * Sum_e p * hin16[src, k] -----
template <int H, int KP, int NPB>
__global__ __launch_bounds__(NPB * KP / 2) void gat_gather(
        const __half* __restrict__ hinf, const __half* __restrict__ palpha,
        const float* __restrict__ zinv, const int* __restrict__ indptr,
        const int* __restrict__ col, __half* __restrict__ g, int N) {
    const int TPN = KP / 2;
    int sub = threadIdx.x / TPN;
    int j   = threadIdx.x % TPN;
    int n = blockIdx.x * NPB + sub;
    if (n >= N) return;
    int c0 = j * 2;
    float acc[H][2];
#pragma unroll
    for (int h = 0; h < H; ++h) { acc[h][0] = 0.f; acc[h][1] = 0.f; }
    int beg = indptr[n], end = indptr[n + 1];
    for (int i = beg; i < end; ++i) {
        int src = col[i];
        __half2 hv = *(const __half2*)(hinf + (size_t)src * KP + c0);
        float2 f = __half22float2(hv);
        const __half2* ap = (const __half2*)(palpha + (size_t)i * H);
#pragma unroll
        for (int h2 = 0; h2 < H / 2; ++h2) {
            float2 aa = __half22float2(ap[h2]);
            acc[2 * h2 + 0][0] += aa.x * f.x;
            acc[2 * h2 + 0][1] += aa.x * f.y;
            acc[2 * h2 + 1][0] += aa.y * f.x;
            acc[2 * h2 + 1][1] += aa.y * f.y;
        }
    }
    __half* gp = g + (size_t)n * (H * KP) + c0;
#pragma unroll
    for (int h = 0; h < H; ++h) {
        float zf = zinv[n * H + h];
        *(__half2*)(gp + h * KP) = __floats2half2_rn(acc[h][0] * zf, acc[h][1] * zf);
    }
}

// ---------------- multi-row-tile split-K MFMA GEMM --------------------------
template <int RT, int SPLIT>
__global__ __launch_bounds__(64) void gemm_mr(const __half* __restrict__ A,
                                              const unsigned short* __restrict__ Bhi,
                                              const unsigned short* __restrict__ Blo,
                                              const float* __restrict__ bias,
                                              const unsigned* __restrict__ masks,
                                              float* __restrict__ P,
                                              __half* __restrict__ O16,
                                              int N, int K, int M) {
    int lane = threadIdx.x;
    int ln16 = lane & 15;
    int q    = lane >> 4;                 // 0..3 (k-octet)
    int row0 = blockIdx.x * (16 * RT);
    int col0 = blockIdx.y * 64;
    int kb   = (K / SPLIT) * blockIdx.z;
    int ke   = kb + K / SPLIT;

    const __half* ap = A + (size_t)(row0 + ln16) * K + q * 8;
    const unsigned short* bhp = Bhi + (size_t)(col0 + ln16) * K + q * 8;
    const unsigned short* blp = Blo + (size_t)(col0 + ln16) * K + q * 8;
    const size_t cstep = (size_t)16 * K;

    f32x4 acc[RT][4];
#pragma unroll
    for (int rt = 0; rt < RT; ++rt)
#pragma unroll
        for (int j = 0; j < 4; ++j) acc[rt][j] = (f32x4){0.f, 0.f, 0.f, 0.f};

#pragma unroll 2
    for (int kc = kb; kc < ke; kc += 32) {
        short8 bh[4], bl[4];
#pragma unroll
        for (int j = 0; j < 4; ++j) {
            bh[j] = *(const short8*)(bhp + (size_t)j * cstep + kc);
            bl[j] = *(const short8*)(blp + (size_t)j * cstep + kc);
        }
        short8 araw[RT];
#pragma unroll
        for (int rt = 0; rt < RT; ++rt)
            araw[rt] = *(const short8*)(ap + (size_t)rt * cstep + kc);
        short8 ah[RT], al[RT];
#pragma unroll
        for (int rt = 0; rt < RT; ++rt) {
#pragma unroll
            for (int i = 0; i < 8; ++i) {
                __half_raw hr;
                hr.x = (unsigned short)araw[rt][i];
                float f = __half2float(*(const __half*)&hr);
                unsigned uu = __float_as_uint(f);
                ah[rt][i] = (short)(uu >> 16);
                float lf = f - __uint_as_float(uu & 0xFFFF0000u);
                al[rt][i] = (short)(__float_as_uint(lf) >> 16);
            }
        }
#pragma unroll
        for (int rt = 0; rt < RT; ++rt) {
#pragma unroll
            for (int j = 0; j < 4; ++j) {
                acc[rt][j] = __builtin_amdgcn_mfma_f32_16x16x32_bf16(ah[rt], bh[j], acc[rt][j], 0, 0, 0);
                acc[rt][j] = __builtin_amdgcn_mfma_f32_16x16x32_bf16(ah[rt], bl[j], acc[rt][j], 0, 0, 0);
                acc[rt][j] = __builtin_amdgcn_mfma_f32_16x16x32_bf16(al[rt], bh[j], acc[rt][j], 0, 0, 0);
            }
        }
    }

    // C/D layout: col = lane&15, row = (lane>>4)*4 + reg
    if (SPLIT == 1) {
#pragma unroll
        for (int rt = 0; rt < RT; ++rt) {
#pragma unroll
            for (int j = 0; j < 4; ++j) {
                int cc = col0 + j * 16 + ln16;
                float bv = bias[cc];
#pragma unroll
                for (int r = 0; r < 4; ++r) {
                    int rr = row0 + rt * 16 + q * 4 + r;
                    if (rr >= N) continue;
                    float v = selu_f(acc[rt][j][r] + bv);
                    if (cc < 2) {
                        unsigned mk = masks[rr];
                        if (cc == 0) { if (mk & 2u) v = 0.f; else if (mk & 1u) v = 1.f; }
                        else         { if (mk & 8u) v = 1.f; else if (mk & 4u) v = 0.f; }
                    }
                    O16[(size_t)rr * M + cc] = __float2half(v);
                }
            }
        }
    } else {
        float* Pz = P + (size_t)blockIdx.z * N * M;
#pragma unroll
        for (int rt = 0; rt < RT; ++rt) {
#pragma unroll
            for (int j = 0; j < 4; ++j) {
                int cc = col0 + j * 16 + ln16;
#pragma unroll
                for (int r = 0; r < 4; ++r) {
                    int rr = row0 + rt * 16 + q * 4 + r;
                    if (rr >= N) continue;
                    Pz[(size_t)rr * M + cc] = acc[rt][j][r];
                }
            }
        }
    }
}

// -------- reduce partials (float4) + bias/selu/boundary -> fp16 -------------
template <int SPLIT>
__global__ __launch_bounds__(256) void reduce_ep(const float* __restrict__ P,
                                                 const float* __restrict__ bias,
                                                 const unsigned* __restrict__ masks,
                                                 __half* __restrict__ O16,
                                                 int N, int M) {
    int t4 = (blockIdx.x * 256 + threadIdx.x) * 4;
    if (t4 >= N * M) return;
    int n = t4 / M, c = t4 - n * M;     // M % 4 == 0, so all 4 share n
    float4 v = *(const float4*)(P + t4);
#pragma unroll
    for (int s = 1; s < SPLIT; ++s) {
        float4 u = *(const float4*)(P + (size_t)s * N * M + t4);
        v.x += u.x; v.y += u.y; v.z += u.z; v.w += u.w;
    }
    float4 bv = *(const float4*)(bias + c);
    float o0 = selu_f(v.x + bv.x), o1 = selu_f(v.y + bv.y);
    float o2 = selu_f(v.z + bv.z), o3 = selu_f(v.w + bv.w);
    if (c == 0) {
        unsigned mk = masks[n];
        if (mk & 2u) o0 = 0.f; else if (mk & 1u) o0 = 1.f;
        if (mk & 8u) o1 = 1.f; else if (mk & 4u) o1 = 0.f;
    }
    __half2* op = (__half2*)(O16 + t4);
    op[0] = __floats2half2_rn(o0, o1);
    op[1] = __floats2half2_rn(o2, o3);
}

// ---------------- final layer (C=2): out = bfix(x + selu(g @ W5s + b5)) -----
__global__ __launch_bounds__(256) void final5_kernel(const __half* __restrict__ g,
                                                     const float* __restrict__ W5,
                                                     const float* __restrict__ b5,
                                                     const unsigned* __restrict__ masks,
                                                     const float* __restrict__ x,
                                                     float* __restrict__ out,
                                                     int N, int KA) {
    int wave = threadIdx.x >> 6, lane = threadIdx.x & 63;
    int n = blockIdx.x * 4 + wave;
    if (n >= N) return;
    float a0 = 0.f, a1 = 0.f;
    const __half* gp = g + (size_t)n * KA;
    for (int k = lane * 2; k < KA; k += 128) {
        float2 f = __half22float2(*(const __half2*)(gp + k));
        float4 w = *(const float4*)(W5 + (size_t)k * 2);
        a0 += f.x * w.x + f.y * w.z;
        a1 += f.x * w.y + f.y * w.w;
    }
#pragma unroll
    for (int off = 32; off >= 1; off >>= 1) {
        a0 += __shfl_xor(a0, off);
        a1 += __shfl_xor(a1, off);
    }
    if (lane == 0) {
        unsigned mk = masks[n];
        float v0 = x[n * 10 + 0] + selu_f(a0 + b5[0]);
        float v1 = x[n * 10 + 1] + selu_f(a1 + b5[1]);
        if (mk & 2u) v0 = 0.f; else if (mk & 1u) v0 = 1.f;
        if (mk & 8u) v1 = 1.f; else if (mk & 4u) v1 = 0.f;
        out[n * 2 + 0] = v0;
        out[n * 2 + 1] = v1;
    }
}

// ---------------------------------------------------------------------------
extern "C" void kernel_launch(void* const* d_in, const int* in_sizes, int n_in,
                              void* d_out, int out_size, void* d_ws, size_t ws_size,
                              hipStream_t stream) {
    const float* x   = (const float*)d_in[0];
    const int*   ei  = (const int*)d_in[1];
    const float* cf  = (const float*)d_in[2];
    const float* cw[4] = {(const float*)d_in[3], (const float*)d_in[5],
                          (const float*)d_in[7], (const float*)d_in[9]};
    const float* cb[4] = {(const float*)d_in[4], (const float*)d_in[6],
                          (const float*)d_in[8], (const float*)d_in[10]};
    const float* gw[5], *gas[5], *gad[5], *gb[5];
    for (int i = 0; i < 5; ++i) {
        gw[i]  = (const float*)d_in[11 + 4 * i];
        gas[i] = (const float*)d_in[12 + 4 * i];
        gad[i] = (const float*)d_in[13 + 4 * i];
        gb[i]  = (const float*)d_in[14 + 4 * i];
    }
    const int N = in_sizes[0] / 10;        // 10000
    const int E = in_sizes[1] / 2;         // 160000
    const int EN = E + N;

    // ---- workspace carve-up ----
    char* base = (char*)d_ws;
    size_t off = 0;
    auto alloc = [&](size_t bytes) -> char* {
        char* p = base + off;
        off = (off + bytes + 255) & ~(size_t)255;
        return p;
    };
    float* cfp   = (float*)alloc((size_t)4 * PSZ * 4);
    float* c1p   = (float*)alloc((size_t)16 * PSZ * 4);
    float* c2p   = (float*)alloc((size_t)32 * PSZ * 4);
    float* c3p   = (float*)alloc((size_t)64 * PSZ * 4);
    float* c4p   = (float*)alloc((size_t)24 * PSZ * 4);
    float* gfeat = (float*)alloc(24 * 4);
    __half* hA16 = (__half*)alloc((size_t)N * 256 * 2);
    __half* hB16 = (__half*)alloc((size_t)N * 256 * 2);
    __half* g    = (__half*)alloc((size_t)N * 2048 * 2);
    float* P     = (float*)alloc((size_t)4 * N * 256 * 4);   // 41 MB partials
    float* escr  = P;                                        // aliased: free at attn time
    float* esed  = (float*)alloc((size_t)N * 32 * 4);
    float* zinv  = (float*)alloc((size_t)N * 16 * 4);
    __half* palpha = (__half*)alloc((size_t)EN * 16 * 2);
    float* wesed = (float*)alloc(256 * 32 * 4);
    float* wstack= (float*)alloc((size_t)2048 * 2 * 4);
    unsigned short* bt_hi = (unsigned short*)alloc((size_t)262144 * 2);
    unsigned short* bt_lo = (unsigned short*)alloc((size_t)262144 * 2);
    unsigned* masks = (unsigned*)alloc((size_t)N * 4);
    int* cnt    = (int*)alloc((size_t)N * 4);
    int* indptr = (int*)alloc((size_t)(N + 1) * 4);
    int* cursor = (int*)alloc((size_t)N * 4);
    int* col    = (int*)alloc((size_t)EN * 4);
    (void)ws_size; // ~112 MB

    // ---- CNN (padded layout; single memset zeroes all borders) ----
    hipMemsetAsync(cfp, 0, (size_t)140 * PSZ * 4, stream);
    pad_input<<<(4 * 4096 + 255) / 256, 256, 0, stream>>>(cf, cfp);
    conv3x3_pad<4><<<dim3(4, 16), 256, 0, stream>>>(cfp, cw[0], cb[0], c1p);
    conv3x3_pad<16><<<dim3(4, 32), 256, 0, stream>>>(c1p, cw[1], cb[1], c2p);
    conv3x3_pad<32><<<dim3(4, 64), 256, 0, stream>>>(c2p, cw[2], cb[2], c3p);
    conv3x3_pad<64><<<dim3(4, 24), 256, 0, stream>>>(c3p, cw[3], cb[3], c4p);
    avgpool_c<<<24, 256, 0, stream>>>(c4p, gfeat);

    // ---- h0 (padded to 48, fp16) + masks ----
    build_h0<<<(N + 255) / 256, 256, 0, stream>>>(x, gfeat, hA16, masks, N);

    // ---- CSR by dst (incl self loops) ----
    hipMemsetAsync(cnt, 0, (size_t)N * 4, stream);
    count_dst<<<(EN + 255) / 256, 256, 0, stream>>>(ei, cnt, E, N);
    exscan_single<<<1, 256, 0, stream>>>(cnt, indptr, N);
    copy_int<<<(N + 255) / 256, 256, 0, stream>>>(indptr, cursor, N);
    scatter_edges<<<(EN + 255) / 256, 256, 0, stream>>>(ei, cursor, col, E, N);

    // ---- GAT layers ----
    const int Ko[5] = {34, 64, 128, 256, 128};   // true input dims
    const int Kp[5] = {48, 64, 128, 256, 128};   // padded
    const int Hs[5] = {8, 16, 8, 8, 16};
    const int Cs[5] = {64, 128, 256, 128, 2};

    const __half* hin16 = hA16;
    __half* hout16[4]  = {hB16, hA16, hB16, hA16};

    for (int lyr = 0; lyr < 5; ++lyr) {
        int K = Ko[lyr], KP = Kp[lyr], H = Hs[lyr], C = Cs[lyr];
        int KA = H * KP;
        build_wesed<<<(KP * 2 * H + 255) / 256, 256, 0, stream>>>(gw[lyr], gas[lyr], gad[lyr],
                                                                  wesed, K, KP, H, C);
        esed_kernel<<<(N * H + 255) / 256, 256, 0, stream>>>(hin16, wesed, esed, N, KP, 2 * H);
        attn_kernel<<<(N * H + 255) / 256, 256, 0, stream>>>(esed, indptr, col, escr,
                                                             palpha, zinv, N, H);
        if (lyr == 0)
            gat_gather<8, 48, 10><<<(N + 9) / 10, 240, 0, stream>>>(hin16, palpha, zinv, indptr, col, g, N);
        else if (lyr == 1)
            gat_gather<16, 64, 8><<<(N + 7) / 8, 256, 0, stream>>>(hin16, palpha, zinv, indptr, col, g, N);
        else if (lyr == 2)
            gat_gather<8, 128, 4><<<(N + 3) / 4, 256, 0, stream>>>(hin16, palpha, zinv, indptr, col, g, N);
        else if (lyr == 3)
            gat_gather<8, 256, 2><<<(N + 1) / 2, 256, 0, stream>>>(hin16, palpha, zinv, indptr, col, g, N);
        else
            gat_gather<16, 128, 4><<<(N + 3) / 4, 256, 0, stream>>>(hin16, palpha, zinv, indptr, col, g, N);

        if (lyr < 4) {
            build_wtb<<<(C * KA + 255) / 256, 256, 0, stream>>>(gw[lyr], bt_hi, bt_lo, K, KP, H, C);
            if (lyr == 0) {            // KA=384, C=64: RT=2, SPLIT=4
                dim3 gg((N + 31) / 32, C / 64, 4);
                gemm_mr<2, 4><<<gg, 64, 0, stream>>>(g, bt_hi, bt_lo, gb[lyr], masks, P, hout16[lyr], N, KA, C);
                reduce_ep<4><<<(N * C / 4 + 255) / 256, 256, 0, stream>>>(P, gb[lyr], masks, hout16[lyr], N, C);
            } else if (lyr == 2) {     // KA=2048, C=256: RT=4, SPLIT=4
                dim3 gg((N + 63) / 64, C / 64, 4);
                gemm_mr<4, 4><<<gg, 64, 0, stream>>>(g, bt_hi, bt_lo, gb[lyr], masks, P, hout16[lyr], N, KA, C);
                reduce_ep<4><<<(N * C / 4 + 255) / 256, 256, 0, stream>>>(P, gb[lyr], masks, hout16[lyr], N, C);
            } else {                   // KA=1024, C=128: RT=2, SPLIT=4
                dim3 gg((N + 31) / 32, C / 64, 4);
                gemm_mr<2, 4><<<gg, 64, 0, stream>>>(g, bt_hi, bt_lo, gb[lyr], masks, P, hout16[lyr], N, KA, C);
                reduce_ep<4><<<(N * C / 4 + 255) / 256, 256, 0, stream>>>(P, gb[lyr], masks, hout16[lyr], N, C);
            }
            hin16 = hout16[lyr];
        } else {
            build_wstack<<<(KA * 2 + 255) / 256, 256, 0, stream>>>(gw[4], wstack, K, KP, H, 2);
            final5_kernel<<<(N + 3) / 4, 256, 0, stream>>>(g, wstack, gb[4], masks, x,
                                                           (float*)d_out, N, KA);
        }
    }
}

// Round 12
// 847.381 us; speedup vs baseline: 1.0647x; 1.0647x over previous
//
#include <hip/hip_runtime.h>
#include <hip/hip_fp16.h>
#include <math.h>

// ---------------------------------------------------------------------------
// NetGlobGATFix. R12: R10 base (874us) + single-pass attention.
//   - attn_kernel: softmax shift-invariance -> no max pass; p = expf(e) in
//     fp32 (safe: |e| << 87), palpha fp32. Halves attention's random gathers.
//   - prep_layer: build_wtb + build_wesed + build_wstack fused (one
//     dispatch/layer instead of 2-3).
//   - exscan writes cursor too (copy_int removed).
//   - CNN (padded 66x66), gemm_mr split-K MFMA, gather, reduce: R10 exact.
// ---------------------------------------------------------------------------

#define DEVFN static __device__ __forceinline__

typedef __attribute__((ext_vector_type(8))) short short8;
typedef __attribute__((ext_vector_type(4))) float f32x4;

DEVFN float selu_f(float v) {
    const float scale = 1.0507009873554805f;
    const float alpha = 1.6732632423543772f;
    return v > 0.f ? scale * v : scale * alpha * (expf(v) - 1.f);
}

DEVFN float lrelu02(float v) { return v > 0.f ? v : 0.2f * v; }

// truncation split: hi = trunc_bf16(a); lo = trunc_bf16(a - hi)
DEVFN void split_bf16(float a, unsigned short& hi, unsigned short& lo) {
    unsigned u = __float_as_uint(a);
    hi = (unsigned short)(u >> 16);
    float hf = __uint_as_float(u & 0xFFFF0000u);
    float l = a - hf;
    lo = (unsigned short)(__float_as_uint(l) >> 16);
}

// ---------------- CNN (padded 66x66 layout) ----------------
#define PST 66
#define PSZ (66 * 66)

__global__ void pad_input(const float* __restrict__ cf, float* __restrict__ out) {
    int t = blockIdx.x * blockDim.x + threadIdx.x;
    if (t >= 4 * 4096) return;
    int c = t >> 12, pix = t & 4095;
    int y = pix >> 6, x = pix & 63;
    out[c * PSZ + (y + 1) * PST + (x + 1)] = cf[t];
}

template <int CIN>
__global__ __launch_bounds__(256) void conv3x3_pad(const float* __restrict__ in,
                                                   const float* __restrict__ w,
                                                   const float* __restrict__ b,
                                                   float* __restrict__ out) {
    int x  = threadIdx.x & 63;
    int yg = threadIdx.x >> 6;
    int y0 = blockIdx.x * 16 + yg * 4;
    int co = blockIdx.y;
    float bv = b[co];
    float acc[4] = {bv, bv, bv, bv};
    const float* wp = w + (size_t)co * CIN * 9;
#pragma unroll 4
    for (int ci = 0; ci < CIN; ++ci) {
        const float* ip = in + ci * PSZ + y0 * PST + x;
        float wr[9];
#pragma unroll
        for (int j = 0; j < 9; ++j) wr[j] = wp[ci * 9 + j];
        float r[6][3];
#pragma unroll
        for (int rr = 0; rr < 6; ++rr) {
            r[rr][0] = ip[rr * PST + 0];
            r[rr][1] = ip[rr * PST + 1];
            r[rr][2] = ip[rr * PST + 2];
        }
#pragma unroll
        for (int v = 0; v < 4; ++v)
#pragma unroll
            for (int ky = 0; ky < 3; ++ky)
#pragma unroll
                for (int kx = 0; kx < 3; ++kx)
                    acc[v] += wr[ky * 3 + kx] * r[v + ky][kx];
    }
#pragma unroll
    for (int v = 0; v < 4; ++v)
        out[(size_t)co * PSZ + (y0 + v + 1) * PST + (x + 1)] = selu_f(acc[v]);
}

__global__ void avgpool_c(const float* __restrict__ in, float* __restrict__ gfeat) {
    int c = blockIdx.x;            // 24 blocks
    int t = threadIdx.x;           // 256 threads
    float s = 0.f;
    for (int i = t; i < 4096; i += 256) {
        int y = i >> 6, x = i & 63;
        s += in[c * PSZ + (y + 1) * PST + (x + 1)];
    }
#pragma unroll
    for (int off = 32; off >= 1; off >>= 1) s += __shfl_xor(s, off);
    __shared__ float red[4];
    int wave = t >> 6, lane = t & 63;
    if (lane == 0) red[wave] = s;
    __syncthreads();
    if (t == 0) gfeat[c] = (red[0] + red[1] + red[2] + red[3]) * (1.f / 4096.f);
}

// ---------------- node feature init (padded to 48 ch, fp16) + masks ---------
__global__ void build_h0(const float* __restrict__ x, const float* __restrict__ gfeat,
                         __half* __restrict__ h0f, unsigned* __restrict__ masks, int N) {
    int n = blockIdx.x * blockDim.x + threadIdx.x;
    if (n >= N) return;
    float x0 = x[n * 10 + 0], x1 = x[n * 10 + 1];
    unsigned mk = (x0 == 1.f ? 1u : 0u) | (x0 == 0.f ? 2u : 0u) |
                  (x1 == 0.f ? 4u : 0u) | (x1 == 1.f ? 8u : 0u);
    masks[n] = mk;
    __half* hq = h0f + (size_t)n * 48;
#pragma unroll
    for (int j = 0; j < 48; ++j) {
        float v = (j < 24) ? gfeat[j] : (j < 34 ? x[n * 10 + (j - 24)] : 0.f);
        hq[j] = __float2half(v);
    }
}

// ---------------- CSR build ----------------
__global__ void count_dst(const int* __restrict__ ei, int* __restrict__ cnt, int E, int N) {
    int t = blockIdx.x * blockDim.x + threadIdx.x;
    if (t >= E + N) return;
    int dst = (t < E) ? ei[E + t] : (t - E);
    atomicAdd(&cnt[dst], 1);
}

// exclusive scan; also writes cursor[i] = indptr[i]
__global__ void exscan_single(const int* __restrict__ cnt, int* __restrict__ indptr,
                              int* __restrict__ cursor, int n) {
    __shared__ int sdata[256];
    __shared__ int run_s;
    int tid = threadIdx.x;
    if (tid == 0) { run_s = 0; indptr[0] = 0; }
    __syncthreads();
    for (int base = 0; base < n; base += 256) {
        int i = base + tid;
        int v = (i < n) ? cnt[i] : 0;
        sdata[tid] = v;
        __syncthreads();
        for (int off = 1; off < 256; off <<= 1) {
            int tmp = (tid >= off) ? sdata[tid - off] : 0;
            __syncthreads();
            sdata[tid] += tmp;
            __syncthreads();
        }
        if (i < n) {
            indptr[i + 1] = run_s + sdata[tid];
            cursor[i] = run_s + sdata[tid] - v;
        }
        __syncthreads();
        if (tid == 0) run_s += sdata[255];
        __syncthreads();
    }
}

__global__ void scatter_edges(const int* __restrict__ ei, int* __restrict__ cursor,
                              int* __restrict__ col, int E, int N) {
    int t = blockIdx.x * blockDim.x + threadIdx.x;
    if (t >= E + N) return;
    int src, dst;
    if (t < E) { src = ei[t]; dst = ei[E + t]; }
    else       { src = dst = t - E; }
    int pos = atomicAdd(&cursor[dst], 1);
    col[pos] = src;
}

// ---------------- fused weight prep -----------------------------------------
// t < nwtb            : Bt hi/lo planes   (layers with C > 2)
// t < nwtb + nws      : wstack fp32       (final layer, C == 2)
// else                : wesed
__global__ void prep_layer(const float* __restrict__ W, const float* __restrict__ as,
                           const float* __restrict__ ad,
                           unsigned short* __restrict__ bhi, unsigned short* __restrict__ blo,
                           float* __restrict__ wstack, float* __restrict__ wesed,
                           int K, int Kp, int H, int C) {
    int KA = H * Kp;
    int H2 = 2 * H;
    int nwtb = (C > 2) ? C * KA : 0;
    int nws  = (C == 2) ? KA * 2 : 0;
    int t = blockIdx.x * blockDim.x + threadIdx.x;
    if (t < nwtb) {
        int ka = t % KA;
        int m  = t / KA;
        int h = ka / Kp, k = ka - h * Kp;
        float v = (k < K) ? W[(size_t)k * (H * C) + h * C + m] : 0.f;
        unsigned short hi, lo;
        split_bf16(v, hi, lo);
        bhi[t] = hi;
        blo[t] = lo;
    } else if (t < nwtb + nws) {
        int u = t - nwtb;
        int c = u & 1, r = u >> 1;           // r = h*Kp + k
        int h = r / Kp, k = r - h * Kp;
        wstack[u] = (k < K) ? W[(size_t)k * (H * C) + h * C + c] : 0.f;
    } else if (t < nwtb + nws + Kp * H2) {
        int u = t - nwtb - nws;
        int k = u / H2, o = u - k * H2;
        float s = 0.f;
        if (k < K) {
            int h = (o < H) ? o : o - H;
            const float* av = ((o < H) ? as : ad) + h * C;
            const float* wp = W + (size_t)k * (H * C) + h * C;
            for (int c = 0; c < C; ++c) s += wp[c] * av[c];
        }
        wesed[u] = s;
    }
}

// ---------------- es/ed: esed[n, o] = hin16[n,:] @ wesed[:,o], o < 2H -------
__global__ void esed_kernel(const __half* __restrict__ hin, const float* __restrict__ wesed,
                            float* __restrict__ esed, int N, int Kp, int H2) {
    int t = blockIdx.x * blockDim.x + threadIdx.x;
    if (t >= N * H2) return;
    int n = t / H2, o = t - n * H2;
    const __half2* hp = (const __half2*)(hin + (size_t)n * Kp);
    float s = 0.f;
    for (int k2 = 0; k2 < Kp / 2; ++k2) {
        float2 f = __half22float2(hp[k2]);
        s += f.x * wesed[(2 * k2) * H2 + o] + f.y * wesed[(2 * k2 + 1) * H2 + o];
    }
    esed[t] = s;
}

// ---------------- attention: single pass (softmax shift-invariant) ----------
// p = expf(e) directly; |e| << 87 at these weight scales, so fp32 exp is safe.
__global__ void attn_kernel(const float* __restrict__ esed,
                            const int* __restrict__ indptr, const int* __restrict__ col,
                            float* __restrict__ palpha, float* __restrict__ zinv,
                            int N, int H) {
    int t = blockIdx.x * blockDim.x + threadIdx.x;
    if (t >= N * H) return;
    int n = t / H, h = t - n * H;
    int H2 = 2 * H;
    float edv = esed[n * H2 + H + h];
    int beg = indptr[n], end = indptr[n + 1];
    float z = 0.f;
    for (int i = beg; i < end; ++i) {
        float e = lrelu02(esed[col[i] * H2 + h] + edv);
        float p = expf(e);
        palpha[(size_t)i * H + h] = p;
        z += p;
    }
    zinv[t] = (1.f / H) / (z + 1e-16f);
}

// ---------------- gather: g[n, h*KP+k] = zinv * Sum_e p * hin16[src, k] -----
template <int H, int KP, int NPB>
__global__ __launch_bounds__(NPB * KP / 2) void gat_gather(
        const __half* __restrict__ hinf, const float* __restrict__ palpha,
        const float* __restrict__ zinv, const int* __restrict__ indptr,
        const int* __restrict__ col, __half* __restrict__ g, int N) {
    const int TPN = KP / 2;
    int sub = threadIdx.x / TPN;
    int j   = threadIdx.x % TPN;
    int n = blockIdx.x * NPB + sub;
    if (n >= N) return;
    int c0 = j * 2;
    float acc[H][2];
#pragma unroll
    for (int h = 0; h < H; ++h) { acc[h][0] = 0.f; acc[h][1] = 0.f; }
    int beg = indptr[n], end = indptr[n + 1];
    for (int i = beg; i < end; ++i) {
        int src = col[i];
        __half2 hv = *(const __half2*)(hinf + (size_t)src * KP + c0);
        float2 f = __half22float2(hv);
        const float2* ap = (const float2*)(palpha + (size_t)i * H);
#pragma unroll
        for (int h2 = 0; h2 < H / 2; ++h2) {
            float2 aa = ap[h2];
            acc[2 * h2 + 0][0] += aa.x * f.x;
            acc[2 * h2 + 0][1] += aa.x * f.y;
            acc[2 * h2 + 1][0] += aa.y * f.x;
            acc[2 * h2 + 1][1] += aa.y * f.y;
        }
    }
    __half* gp = g + (size_t)n * (H * KP) + c0;
#pragma unroll
    for (int h = 0; h < H; ++h) {
        float zf = zinv[n * H + h];
        *(__half2*)(gp + h * KP) = __floats2half2_rn(acc[h][0] * zf, acc[h][1] * zf);
    }
}

// ---------------- multi-row-tile split-K MFMA GEMM --------------------------
template <int RT, int SPLIT>
__global__ __launch_bounds__(64) void gemm_mr(const __half* __restrict__ A,
                                              const unsigned short* __restrict__ Bhi,
                                              const unsigned short* __restrict__ Blo,
                                              const float* __restrict__ bias,
                                              const unsigned* __restrict__ masks,
                                              float* __restrict__ P,
                                              __half* __restrict__ O16,
                                              int N, int K, int M) {
    int lane = threadIdx.x;
    int ln16 = lane & 15;
    int q    = lane >> 4;                 // 0..3 (k-octet)
    int row0 = blockIdx.x * (16 * RT);
    int col0 = blockIdx.y * 64;
    int kb   = (K / SPLIT) * blockIdx.z;
    int ke   = kb + K / SPLIT;

    const __half* ap = A + (size_t)(row0 + ln16) * K + q * 8;
    const unsigned short* bhp = Bhi + (size_t)(col0 + ln16) * K + q * 8;
    const unsigned short* blp = Blo + (size_t)(col0 + ln16) * K + q * 8;
    const size_t cstep = (size_t)16 * K;

    f32x4 acc[RT][4];
#pragma unroll
    for (int rt = 0; rt < RT; ++rt)
#pragma unroll
        for (int j = 0; j < 4; ++j) acc[rt][j] = (f32x4){0.f, 0.f, 0.f, 0.f};

#pragma unroll 2
    for (int kc = kb; kc < ke; kc += 32) {
        short8 bh[4], bl[4];
#pragma unroll
        for (int j = 0; j < 4; ++j) {
            bh[j] = *(const short8*)(bhp + (size_t)j * cstep + kc);
            bl[j] = *(const short8*)(blp + (size_t)j * cstep + kc);
        }
        short8 araw[RT];
#pragma unroll
        for (int rt = 0; rt < RT; ++rt)
            araw[rt] = *(const short8*)(ap + (size_t)rt * cstep + kc);
        short8 ah[RT], al[RT];
#pragma unroll
        for (int rt = 0; rt < RT; ++rt) {
#pragma unroll
            for (int i = 0; i < 8; ++i) {
                __half_raw hr;
                hr.x = (unsigned short)araw[rt][i];
                float f = __half2float(*(const __half*)&hr);
                unsigned uu = __float_as_uint(f);
                ah[rt][i] = (short)(uu >> 16);
                float lf = f - __uint_as_float(uu & 0xFFFF0000u);
                al[rt][i] = (short)(__float_as_uint(lf) >> 16);
            }
        }
#pragma unroll
        for (int rt = 0; rt < RT; ++rt) {
#pragma unroll
            for (int j = 0; j < 4; ++j) {
                acc[rt][j] = __builtin_amdgcn_mfma_f32_16x16x32_bf16(ah[rt], bh[j], acc[rt][j], 0, 0, 0);
                acc[rt][j] = __builtin_amdgcn_mfma_f32_16x16x32_bf16(ah[rt], bl[j], acc[rt][j], 0, 0, 0);
                acc[rt][j] = __builtin_amdgcn_mfma_f32_16x16x32_bf16(al[rt], bh[j], acc[rt][j], 0, 0, 0);
            }
        }
    }

    // C/D layout: col = lane&15, row = (lane>>4)*4 + reg
    if (SPLIT == 1) {
#pragma unroll
        for (int rt = 0; rt < RT; ++rt) {
#pragma unroll
            for (int j = 0; j < 4; ++j) {
                int cc = col0 + j * 16 + ln16;
                float bv = bias[cc];
#pragma unroll
                for (int r = 0; r < 4; ++r) {
                    int rr = row0 + rt * 16 + q * 4 + r;
                    if (rr >= N) continue;
                    float v = selu_f(acc[rt][j][r] + bv);
                    if (cc < 2) {
                        unsigned mk = masks[rr];
                        if (cc == 0) { if (mk & 2u) v = 0.f; else if (mk & 1u) v = 1.f; }
                        else         { if (mk & 8u) v = 1.f; else if (mk & 4u) v = 0.f; }
                    }
                    O16[(size_t)rr * M + cc] = __float2half(v);
                }
            }
        }
    } else {
        float* Pz = P + (size_t)blockIdx.z * N * M;
#pragma unroll
        for (int rt = 0; rt < RT; ++rt) {
#pragma unroll
            for (int j = 0; j < 4; ++j) {
                int cc = col0 + j * 16 + ln16;
#pragma unroll
                for (int r = 0; r < 4; ++r) {
                    int rr = row0 + rt * 16 + q * 4 + r;
                    if (rr >= N) continue;
                    Pz[(size_t)rr * M + cc] = acc[rt][j][r];
                }
            }
        }
    }
}

// ---------------- reduce partials + bias/selu/boundary -> fp16 --------------
template <int SPLIT>
__global__ __launch_bounds__(256) void reduce_ep(const float* __restrict__ P,
                                                 const float* __restrict__ bias,
                                                 const unsigned* __restrict__ masks,
                                                 __half* __restrict__ O16,
                                                 int N, int M) {
    int t = blockIdx.x * 256 + threadIdx.x;
    if (t >= N * M) return;
    int n = t / M, c = t - n * M;
    float v = 0.f;
#pragma unroll
    for (int s = 0; s < SPLIT; ++s) v += P[(size_t)s * N * M + t];
    v = selu_f(v + bias[c]);
    if (c < 2) {
        unsigned mk = masks[n];
        if (c == 0) { if (mk & 2u) v = 0.f; else if (mk & 1u) v = 1.f; }
        else        { if (mk & 8u) v = 1.f; else if (mk & 4u) v = 0.f; }
    }
    O16[t] = __float2half(v);
}

// ---------------- final layer (C=2): out = bfix(x + selu(g @ W5s + b5)) -----
__global__ __launch_bounds__(256) void final5_kernel(const __half* __restrict__ g,
                                                     const float* __restrict__ W5,
                                                     const float* __restrict__ b5,
                                                     const unsigned* __restrict__ masks,
                                                     const float* __restrict__ x,
                                                     float* __restrict__ out,
                                                     int N, int KA) {
    int wave = threadIdx.x >> 6, lane = threadIdx.x & 63;
    int n = blockIdx.x * 4 + wave;
    if (n >= N) return;
    float a0 = 0.f, a1 = 0.f;
    const __half* gp = g + (size_t)n * KA;
    for (int k = lane * 2; k < KA; k += 128) {
        float2 f = __half22float2(*(const __half2*)(gp + k));
        float4 w = *(const float4*)(W5 + (size_t)k * 2);
        a0 += f.x * w.x + f.y * w.z;
        a1 += f.x * w.y + f.y * w.w;
    }
#pragma unroll
    for (int off = 32; off >= 1; off >>= 1) {
        a0 += __shfl_xor(a0, off);
        a1 += __shfl_xor(a1, off);
    }
    if (lane == 0) {
        unsigned mk = masks[n];
        float v0 = x[n * 10 + 0] + selu_f(a0 + b5[0]);
        float v1 = x[n * 10 + 1] + selu_f(a1 + b5[1]);
        if (mk & 2u) v0 = 0.f; else if (mk & 1u) v0 = 1.f;
        if (mk & 8u) v1 = 1.f; else if (mk & 4u) v1 = 0.f;
        out[n * 2 + 0] = v0;
        out[n * 2 + 1] = v1;
    }
}

// ---------------------------------------------------------------------------
extern "C" void kernel_launch(void* const* d_in, const int* in_sizes, int n_in,
                              void* d_out, int out_size, void* d_ws, size_t ws_size,
                              hipStream_t stream) {
    const float* x   = (const float*)d_in[0];
    const int*   ei  = (const int*)d_in[1];
    const float* cf  = (const float*)d_in[2];
    const float* cw[4] = {(const float*)d_in[3], (const float*)d_in[5],
                          (const float*)d_in[7], (const float*)d_in[9]};
    const float* cb[4] = {(const float*)d_in[4], (const float*)d_in[6],
                          (const float*)d_in[8], (const float*)d_in[10]};
    const float* gw[5], *gas[5], *gad[5], *gb[5];
    for (int i = 0; i < 5; ++i) {
        gw[i]  = (const float*)d_in[11 + 4 * i];
        gas[i] = (const float*)d_in[12 + 4 * i];
        gad[i] = (const float*)d_in[13 + 4 * i];
        gb[i]  = (const float*)d_in[14 + 4 * i];
    }
    const int N = in_sizes[0] / 10;        // 10000
    const int E = in_sizes[1] / 2;         // 160000
    const int EN = E + N;

    // ---- workspace carve-up ----
    char* base = (char*)d_ws;
    size_t off = 0;
    auto alloc = [&](size_t bytes) -> char* {
        char* p = base + off;
        off = (off + bytes + 255) & ~(size_t)255;
        return p;
    };
    float* cfp   = (float*)alloc((size_t)4 * PSZ * 4);
    float* c1p   = (float*)alloc((size_t)16 * PSZ * 4);
    float* c2p   = (float*)alloc((size_t)32 * PSZ * 4);
    float* c3p   = (float*)alloc((size_t)64 * PSZ * 4);
    float* c4p   = (float*)alloc((size_t)24 * PSZ * 4);
    float* gfeat = (float*)alloc(24 * 4);
    __half* hA16 = (__half*)alloc((size_t)N * 256 * 2);
    __half* hB16 = (__half*)alloc((size_t)N * 256 * 2);
    __half* g    = (__half*)alloc((size_t)N * 2048 * 2);
    float* P     = (float*)alloc((size_t)4 * N * 256 * 4);   // 41 MB partials
    float* esed  = (float*)alloc((size_t)N * 32 * 4);
    float* zinv  = (float*)alloc((size_t)N * 16 * 4);
    float* palpha = (float*)alloc((size_t)EN * 16 * 4);      // fp32 numerators
    float* wesed = (float*)alloc(256 * 32 * 4);
    float* wstack= (float*)alloc((size_t)2048 * 2 * 4);
    unsigned short* bt_hi = (unsigned short*)alloc((size_t)524288 * 2);
    unsigned short* bt_lo = (unsigned short*)alloc((size_t)524288 * 2);
    unsigned* masks = (unsigned*)alloc((size_t)N * 4);
    int* cnt    = (int*)alloc((size_t)N * 4);
    int* indptr = (int*)alloc((size_t)(N + 1) * 4);
    int* cursor = (int*)alloc((size_t)N * 4);
    int* col    = (int*)alloc((size_t)EN * 4);
    (void)ws_size; // ~120 MB

    // ---- CNN (padded layout; single memset zeroes all borders) ----
    hipMemsetAsync(cfp, 0, (size_t)140 * PSZ * 4, stream);
    pad_input<<<(4 * 4096 + 255) / 256, 256, 0, stream>>>(cf, cfp);
    conv3x3_pad<4><<<dim3(4, 16), 256, 0, stream>>>(cfp, cw[0], cb[0], c1p);
    conv3x3_pad<16><<<dim3(4, 32), 256, 0, stream>>>(c1p, cw[1], cb[1], c2p);
    conv3x3_pad<32><<<dim3(4, 64), 256, 0, stream>>>(c2p, cw[2], cb[2], c3p);
    conv3x3_pad<64><<<dim3(4, 24), 256, 0, stream>>>(c3p, cw[3], cb[3], c4p);
    avgpool_c<<<24, 256, 0, stream>>>(c4p, gfeat);

    // ---- h0 (padded to 48, fp16) + masks ----
    build_h0<<<(N + 255) / 256, 256, 0, stream>>>(x, gfeat, hA16, masks, N);

    // ---- CSR by dst (incl self loops) ----
    hipMemsetAsync(cnt, 0, (size_t)N * 4, stream);
    count_dst<<<(EN + 255) / 256, 256, 0, stream>>>(ei, cnt, E, N);
    exscan_single<<<1, 256, 0, stream>>>(cnt, indptr, cursor, N);
    scatter_edges<<<(EN + 255) / 256, 256, 0, stream>>>(ei, cursor, col, E, N);

    // ---- GAT layers ----
    const int Ko[5] = {34, 64, 128, 256, 128};   // true input dims
    const int Kp[5] = {48, 64, 128, 256, 128};   // padded
    const int Hs[5] = {8, 16, 8, 8, 16};
    const int Cs[5] = {64, 128, 256, 128, 2};

    const __half* hin16 = hA16;
    __half* hout16[4]  = {hB16, hA16, hB16, hA16};

    for (int lyr = 0; lyr < 5; ++lyr) {
        int K = Ko[lyr], KP = Kp[lyr], H = Hs[lyr], C = Cs[lyr];
        int KA = H * KP;
        int nprep = ((C > 2) ? C * KA : KA * 2) + KP * 2 * H;
        prep_layer<<<(nprep + 255) / 256, 256, 0, stream>>>(gw[lyr], gas[lyr], gad[lyr],
                                                            bt_hi, bt_lo, wstack, wesed,
                                                            K, KP, H, C);
        esed_kernel<<<(N * 2 * H + 255) / 256, 256, 0, stream>>>(hin16, wesed, esed, N, KP, 2 * H);
        attn_kernel<<<(N * H + 255) / 256, 256, 0, stream>>>(esed, indptr, col,
                                                             palpha, zinv, N, H);
        if (lyr == 0)
            gat_gather<8, 48, 10><<<(N + 9) / 10, 240, 0, stream>>>(hin16, palpha, zinv, indptr, col, g, N);
        else if (lyr == 1)
            gat_gather<16, 64, 8><<<(N + 7) / 8, 256, 0, stream>>>(hin16, palpha, zinv, indptr, col, g, N);
        else if (lyr == 2)
            gat_gather<8, 128, 4><<<(N + 3) / 4, 256, 0, stream>>>(hin16, palpha, zinv, indptr, col, g, N);
        else if (lyr == 3)
            gat_gather<8, 256, 2><<<(N + 1) / 2, 256, 0, stream>>>(hin16, palpha, zinv, indptr, col, g, N);
        else
            gat_gather<16, 128, 4><<<(N + 3) / 4, 256, 0, stream>>>(hin16, palpha, zinv, indptr, col, g, N);

        if (lyr < 4) {
            if (lyr == 0) {            // KA=384, C=64: RT=2, SPLIT=4
                dim3 gg((N + 31) / 32, C / 64, 4);
                gemm_mr<2, 4><<<gg, 64, 0, stream>>>(g, bt_hi, bt_lo, gb[lyr], masks, P, hout16[lyr], N, KA, C);
                reduce_ep<4><<<(N * C + 255) / 256, 256, 0, stream>>>(P, gb[lyr], masks, hout16[lyr], N, C);
            } else if (lyr == 2) {     // KA=2048, C=256: RT=4, SPLIT=4
                dim3 gg((N + 63) / 64, C / 64, 4);
                gemm_mr<4, 4><<<gg, 64, 0, stream>>>(g, bt_hi, bt_lo, gb[lyr], masks, P, hout16[lyr], N, KA, C);
                reduce_ep<4><<<(N * C + 255) / 256, 256, 0, stream>>>(P, gb[lyr], masks, hout16[lyr], N, C);
            } else {                   // KA=1024, C=128: RT=2, SPLIT=4
                dim3 gg((N + 31) / 32, C / 64, 4);
                gemm_mr<2, 4><<<gg, 64, 0, stream>>>(g, bt_hi, bt_lo, gb[lyr], masks, P, hout16[lyr], N, KA, C);
                reduce_ep<4><<<(N * C + 255) / 256, 256, 0, stream>>>(P, gb[lyr], masks, hout16[lyr], N, C);
            }
            hin16 = hout16[lyr];
        } else {
            final5_kernel<<<(N + 3) / 4, 256, 0, stream>>>(g, wstack, gb[4], masks, x,
                                                           (float*)d_out, N, KA);
        }
    }
}

// Round 13
// 841.491 us; speedup vs baseline: 1.0721x; 1.0070x over previous
//
#include <hip/hip_runtime.h>
#include <hip/hip_fp16.h>
#include <math.h>

// ---------------------------------------------------------------------------
// NetGlobGATFix. R13: f16-MFMA GEMM (removes in-register split VALU).
//   - B pre-split into fp16-hi + fp16-lo planes (err ~2^-22, better than the
//     old bf16 hi/lo pair); A consumed directly as fp16.
//   - gemm_mr inner loop: 2 f16 MFMAs per (rt,j) instead of 3 bf16 MFMAs +
//     ~380 cyc/chunk of split VALU.
//   - Everything else identical to R12 (847us): padded CNN, single-pass attn,
//     fused prep, split-K partials + reduce.
// ---------------------------------------------------------------------------

#define DEVFN static __device__ __forceinline__

typedef __attribute__((ext_vector_type(8))) _Float16 half8;
typedef __attribute__((ext_vector_type(4))) float f32x4;

DEVFN float selu_f(float v) {
    const float scale = 1.0507009873554805f;
    const float alpha = 1.6732632423543772f;
    return v > 0.f ? scale * v : scale * alpha * (expf(v) - 1.f);
}

DEVFN float lrelu02(float v) { return v > 0.f ? v : 0.2f * v; }

// ---------------- CNN (padded 66x66 layout) ----------------
#define PST 66
#define PSZ (66 * 66)

__global__ void pad_input(const float* __restrict__ cf, float* __restrict__ out) {
    int t = blockIdx.x * blockDim.x + threadIdx.x;
    if (t >= 4 * 4096) return;
    int c = t >> 12, pix = t & 4095;
    int y = pix >> 6, x = pix & 63;
    out[c * PSZ + (y + 1) * PST + (x + 1)] = cf[t];
}

template <int CIN>
__global__ __launch_bounds__(256) void conv3x3_pad(const float* __restrict__ in,
                                                   const float* __restrict__ w,
                                                   const float* __restrict__ b,
                                                   float* __restrict__ out) {
    int x  = threadIdx.x & 63;
    int yg = threadIdx.x >> 6;
    int y0 = blockIdx.x * 16 + yg * 4;
    int co = blockIdx.y;
    float bv = b[co];
    float acc[4] = {bv, bv, bv, bv};
    const float* wp = w + (size_t)co * CIN * 9;
#pragma unroll 4
    for (int ci = 0; ci < CIN; ++ci) {
        const float* ip = in + ci * PSZ + y0 * PST + x;
        float wr[9];
#pragma unroll
        for (int j = 0; j < 9; ++j) wr[j] = wp[ci * 9 + j];
        float r[6][3];
#pragma unroll
        for (int rr = 0; rr < 6; ++rr) {
            r[rr][0] = ip[rr * PST + 0];
            r[rr][1] = ip[rr * PST + 1];
            r[rr][2] = ip[rr * PST + 2];
        }
#pragma unroll
        for (int v = 0; v < 4; ++v)
#pragma unroll
            for (int ky = 0; ky < 3; ++ky)
#pragma unroll
                for (int kx = 0; kx < 3; ++kx)
                    acc[v] += wr[ky * 3 + kx] * r[v + ky][kx];
    }
#pragma unroll
    for (int v = 0; v < 4; ++v)
        out[(size_t)co * PSZ + (y0 + v + 1) * PST + (x + 1)] = selu_f(acc[v]);
}

__global__ void avgpool_c(const float* __restrict__ in, float* __restrict__ gfeat) {
    int c = blockIdx.x;            // 24 blocks
    int t = threadIdx.x;           // 256 threads
    float s = 0.f;
    for (int i = t; i < 4096; i += 256) {
        int y = i >> 6, x = i & 63;
        s += in[c * PSZ + (y + 1) * PST + (x + 1)];
    }
#pragma unroll
    for (int off = 32; off >= 1; off >>= 1) s += __shfl_xor(s, off);
    __shared__ float red[4];
    int wave = t >> 6, lane = t & 63;
    if (lane == 0) red[wave] = s;
    __syncthreads();
    if (t == 0) gfeat[c] = (red[0] + red[1] + red[2] + red[3]) * (1.f / 4096.f);
}

// ---------------- node feature init (padded to 48 ch, fp16) + masks ---------
__global__ void build_h0(const float* __restrict__ x, const float* __restrict__ gfeat,
                         __half* __restrict__ h0f, unsigned* __restrict__ masks, int N) {
    int n = blockIdx.x * blockDim.x + threadIdx.x;
    if (n >= N) return;
    float x0 = x[n * 10 + 0], x1 = x[n * 10 + 1];
    unsigned mk = (x0 == 1.f ? 1u : 0u) | (x0 == 0.f ? 2u : 0u) |
                  (x1 == 0.f ? 4u : 0u) | (x1 == 1.f ? 8u : 0u);
    masks[n] = mk;
    __half* hq = h0f + (size_t)n * 48;
#pragma unroll
    for (int j = 0; j < 48; ++j) {
        float v = (j < 24) ? gfeat[j] : (j < 34 ? x[n * 10 + (j - 24)] : 0.f);
        hq[j] = __float2half(v);
    }
}

// ---------------- CSR build ----------------
__global__ void count_dst(const int* __restrict__ ei, int* __restrict__ cnt, int E, int N) {
    int t = blockIdx.x * blockDim.x + threadIdx.x;
    if (t >= E + N) return;
    int dst = (t < E) ? ei[E + t] : (t - E);
    atomicAdd(&cnt[dst], 1);
}

// exclusive scan; also writes cursor[i] = indptr[i]
__global__ void exscan_single(const int* __restrict__ cnt, int* __restrict__ indptr,
                              int* __restrict__ cursor, int n) {
    __shared__ int sdata[256];
    __shared__ int run_s;
    int tid = threadIdx.x;
    if (tid == 0) { run_s = 0; indptr[0] = 0; }
    __syncthreads();
    for (int base = 0; base < n; base += 256) {
        int i = base + tid;
        int v = (i < n) ? cnt[i] : 0;
        sdata[tid] = v;
        __syncthreads();
        for (int off = 1; off < 256; off <<= 1) {
            int tmp = (tid >= off) ? sdata[tid - off] : 0;
            __syncthreads();
            sdata[tid] += tmp;
            __syncthreads();
        }
        if (i < n) {
            indptr[i + 1] = run_s + sdata[tid];
            cursor[i] = run_s + sdata[tid] - v;
        }
        __syncthreads();
        if (tid == 0) run_s += sdata[255];
        __syncthreads();
    }
}

__global__ void scatter_edges(const int* __restrict__ ei, int* __restrict__ cursor,
                              int* __restrict__ col, int E, int N) {
    int t = blockIdx.x * blockDim.x + threadIdx.x;
    if (t >= E + N) return;
    int src, dst;
    if (t < E) { src = ei[t]; dst = ei[E + t]; }
    else       { src = dst = t - E; }
    int pos = atomicAdd(&cursor[dst], 1);
    col[pos] = src;
}

// ---------------- fused weight prep -----------------------------------------
// Bt planes now fp16 hi/lo: hi = rn_f16(v), lo = rn_f16(v - hi).
__global__ void prep_layer(const float* __restrict__ W, const float* __restrict__ as,
                           const float* __restrict__ ad,
                           unsigned short* __restrict__ bhi, unsigned short* __restrict__ blo,
                           float* __restrict__ wstack, float* __restrict__ wesed,
                           int K, int Kp, int H, int C) {
    int KA = H * Kp;
    int H2 = 2 * H;
    int nwtb = (C > 2) ? C * KA : 0;
    int nws  = (C == 2) ? KA * 2 : 0;
    int t = blockIdx.x * blockDim.x + threadIdx.x;
    if (t < nwtb) {
        int ka = t % KA;
        int m  = t / KA;
        int h = ka / Kp, k = ka - h * Kp;
        float v = (k < K) ? W[(size_t)k * (H * C) + h * C + m] : 0.f;
        __half hv = __float2half(v);
        __half lv = __float2half(v - __half2float(hv));
        bhi[t] = __half_as_ushort(hv);
        blo[t] = __half_as_ushort(lv);
    } else if (t < nwtb + nws) {
        int u = t - nwtb;
        int c = u & 1, r = u >> 1;           // r = h*Kp + k
        int h = r / Kp, k = r - h * Kp;
        wstack[u] = (k < K) ? W[(size_t)k * (H * C) + h * C + c] : 0.f;
    } else if (t < nwtb + nws + Kp * H2) {
        int u = t - nwtb - nws;
        int k = u / H2, o = u - k * H2;
        float s = 0.f;
        if (k < K) {
            int h = (o < H) ? o : o - H;
            const float* av = ((o < H) ? as : ad) + h * C;
            const float* wp = W + (size_t)k * (H * C) + h * C;
            for (int c = 0; c < C; ++c) s += wp[c] * av[c];
        }
        wesed[u] = s;
    }
}

// ---------------- es/ed: esed[n, o] = hin16[n,:] @ wesed[:,o], o < 2H -------
__global__ void esed_kernel(const __half* __restrict__ hin, const float* __restrict__ wesed,
                            float* __restrict__ esed, int N, int Kp, int H2) {
    int t = blockIdx.x * blockDim.x + threadIdx.x;
    if (t >= N * H2) return;
    int n = t / H2, o = t - n * H2;
    const __half2* hp = (const __half2*)(hin + (size_t)n * Kp);
    float s = 0.f;
    for (int k2 = 0; k2 < Kp / 2; ++k2) {
        float2 f = __half22float2(hp[k2]);
        s += f.x * wesed[(2 * k2) * H2 + o] + f.y * wesed[(2 * k2 + 1) * H2 + o];
    }
    esed[t] = s;
}

// ---------------- attention: single pass (softmax shift-invariant) ----------
__global__ void attn_kernel(const float* __restrict__ esed,
                            const int* __restrict__ indptr, const int* __restrict__ col,
                            float* __restrict__ palpha, float* __restrict__ zinv,
                            int N, int H) {
    int t = blockIdx.x * blockDim.x + threadIdx.x;
    if (t >= N * H) return;
    int n = t / H, h = t - n * H;
    int H2 = 2 * H;
    float edv = esed[n * H2 + H + h];
    int beg = indptr[n], end = indptr[n + 1];
    float z = 0.f;
    for (int i = beg; i < end; ++i) {
        float e = lrelu02(esed[col[i] * H2 + h] + edv);
        float p = expf(e);
        palpha[(size_t)i * H + h] = p;
        z += p;
    }
    zinv[t] = (1.f / H) / (z + 1e-16f);
}

// ---------------- gather: g[n, h*KP+k] = zinv * Sum_e p * hin16[src, k] -----
template <int H, int KP, int NPB>
__global__ __launch_bounds__(NPB * KP / 2) void gat_gather(
        const __half* __restrict__ hinf, const float* __restrict__ palpha,
        const float* __restrict__ zinv, const int* __restrict__ indptr,
        const int* __restrict__ col, __half* __restrict__ g, int N) {
    const int TPN = KP / 2;
    int sub = threadIdx.x / TPN;
    int j   = threadIdx.x % TPN;
    int n = blockIdx.x * NPB + sub;
    if (n >= N) return;
    int c0 = j * 2;
    float acc[H][2];
#pragma unroll
    for (int h = 0; h < H; ++h) { acc[h][0] = 0.f; acc[h][1] = 0.f; }
    int beg = indptr[n], end = indptr[n + 1];
    for (int i = beg; i < end; ++i) {
        int src = col[i];
        __half2 hv = *(const __half2*)(hinf + (size_t)src * KP + c0);
        float2 f = __half22float2(hv);
        const float2* ap = (const float2*)(palpha + (size_t)i * H);
#pragma unroll
        for (int h2 = 0; h2 < H / 2; ++h2) {
            float2 aa = ap[h2];
            acc[2 * h2 + 0][0] += aa.x * f.x;
            acc[2 * h2 + 0][1] += aa.x * f.y;
            acc[2 * h2 + 1][0] += aa.y * f.x;
            acc[2 * h2 + 1][1] += aa.y * f.y;
        }
    }
    __half* gp = g + (size_t)n * (H * KP) + c0;
#pragma unroll
    for (int h = 0; h < H; ++h) {
        float zf = zinv[n * H + h];
        *(__half2*)(gp + h * KP) = __floats2half2_rn(acc[h][0] * zf, acc[h][1] * zf);
    }
}

// ---------------- multi-row-tile split-K f16 MFMA GEMM ----------------------
// A fp16 [N x K], Bt fp16 hi/lo [M x K]. Per (rt,j): 2 f16 MFMAs, no split.
template <int RT, int SPLIT>
__global__ __launch_bounds__(64) void gemm_mr(const __half* __restrict__ A,
                                              const unsigned short* __restrict__ Bhi,
                                              const unsigned short* __restrict__ Blo,
                                              const float* __restrict__ bias,
                                              const unsigned* __restrict__ masks,
                                              float* __restrict__ P,
                                              __half* __restrict__ O16,
                                              int N, int K, int M) {
    int lane = threadIdx.x;
    int ln16 = lane & 15;
    int q    = lane >> 4;                 // 0..3 (k-octet)
    int row0 = blockIdx.x * (16 * RT);
    int col0 = blockIdx.y * 64;
    int kb   = (K / SPLIT) * blockIdx.z;
    int ke   = kb + K / SPLIT;

    const __half* ap = A + (size_t)(row0 + ln16) * K + q * 8;
    const unsigned short* bhp = Bhi + (size_t)(col0 + ln16) * K + q * 8;
    const unsigned short* blp = Blo + (size_t)(col0 + ln16) * K + q * 8;
    const size_t cstep = (size_t)16 * K;

    f32x4 acc[RT][4];
#pragma unroll
    for (int rt = 0; rt < RT; ++rt)
#pragma unroll
        for (int j = 0; j < 4; ++j) acc[rt][j] = (f32x4){0.f, 0.f, 0.f, 0.f};

#pragma unroll 2
    for (int kc = kb; kc < ke; kc += 32) {
        half8 bh[4], bl[4];
#pragma unroll
        for (int j = 0; j < 4; ++j) {
            bh[j] = *(const half8*)(bhp + (size_t)j * cstep + kc);
            bl[j] = *(const half8*)(blp + (size_t)j * cstep + kc);
        }
        half8 a[RT];
#pragma unroll
        for (int rt = 0; rt < RT; ++rt)
            a[rt] = *(const half8*)(ap + (size_t)rt * cstep + kc);
#pragma unroll
        for (int rt = 0; rt < RT; ++rt) {
#pragma unroll
            for (int j = 0; j < 4; ++j) {
                acc[rt][j] = __builtin_amdgcn_mfma_f32_16x16x32_f16(a[rt], bh[j], acc[rt][j], 0, 0, 0);
                acc[rt][j] = __builtin_amdgcn_mfma_f32_16x16x32_f16(a[rt], bl[j], acc[rt][j], 0, 0, 0);
            }
        }
    }

    // C/D layout: col = lane&15, row = (lane>>4)*4 + reg
    if (SPLIT == 1) {
#pragma unroll
        for (int rt = 0; rt < RT; ++rt) {
#pragma unroll
            for (int j = 0; j < 4; ++j) {
                int cc = col0 + j * 16 + ln16;
                float bv = bias[cc];
#pragma unroll
                for (int r = 0; r < 4; ++r) {
                    int rr = row0 + rt * 16 + q * 4 + r;
                    if (rr >= N) continue;
                    float v = selu_f(acc[rt][j][r] + bv);
                    if (cc < 2) {
                        unsigned mk = masks[rr];
                        if (cc == 0) { if (mk & 2u) v = 0.f; else if (mk & 1u) v = 1.f; }
                        else         { if (mk & 8u) v = 1.f; else if (mk & 4u) v = 0.f; }
                    }
                    O16[(size_t)rr * M + cc] = __float2half(v);
                }
            }
        }
    } else {
        float* Pz = P + (size_t)blockIdx.z * N * M;
#pragma unroll
        for (int rt = 0; rt < RT; ++rt) {
#pragma unroll
            for (int j = 0; j < 4; ++j) {
                int cc = col0 + j * 16 + ln16;
#pragma unroll
                for (int r = 0; r < 4; ++r) {
                    int rr = row0 + rt * 16 + q * 4 + r;
                    if (rr >= N) continue;
                    Pz[(size_t)rr * M + cc] = acc[rt][j][r];
                }
            }
        }
    }
}

// ---------------- reduce partials + bias/selu/boundary -> fp16 --------------
template <int SPLIT>
__global__ __launch_bounds__(256) void reduce_ep(const float* __restrict__ P,
                                                 const float* __restrict__ bias,
                                                 const unsigned* __restrict__ masks,
                                                 __half* __restrict__ O16,
                                                 int N, int M) {
    int t = blockIdx.x * 256 + threadIdx.x;
    if (t >= N * M) return;
    int n = t / M, c = t - n * M;
    float v = 0.f;
#pragma unroll
    for (int s = 0; s < SPLIT; ++s) v += P[(size_t)s * N * M + t];
    v = selu_f(v + bias[c]);
    if (c < 2) {
        unsigned mk = masks[n];
        if (c == 0) { if (mk & 2u) v = 0.f; else if (mk & 1u) v = 1.f; }
        else        { if (mk & 8u) v = 1.f; else if (mk & 4u) v = 0.f; }
    }
    O16[t] = __float2half(v);
}

// ---------------- final layer (C=2): out = bfix(x + selu(g @ W5s + b5)) -----
__global__ __launch_bounds__(256) void final5_kernel(const __half* __restrict__ g,
                                                     const float* __restrict__ W5,
                                                     const float* __restrict__ b5,
                                                     const unsigned* __restrict__ masks,
                                                     const float* __restrict__ x,
                                                     float* __restrict__ out,
                                                     int N, int KA) {
    int wave = threadIdx.x >> 6, lane = threadIdx.x & 63;
    int n = blockIdx.x * 4 + wave;
    if (n >= N) return;
    float a0 = 0.f, a1 = 0.f;
    const __half* gp = g + (size_t)n * KA;
    for (int k = lane * 2; k < KA; k += 128) {
        float2 f = __half22float2(*(const __half2*)(gp + k));
        float4 w = *(const float4*)(W5 + (size_t)k * 2);
        a0 += f.x * w.x + f.y * w.z;
        a1 += f.x * w.y + f.y * w.w;
    }
#pragma unroll
    for (int off = 32; off >= 1; off >>= 1) {
        a0 += __shfl_xor(a0, off);
        a1 += __shfl_xor(a1, off);
    }
    if (lane == 0) {
        unsigned mk = masks[n];
        float v0 = x[n * 10 + 0] + selu_f(a0 + b5[0]);
        float v1 = x[n * 10 + 1] + selu_f(a1 + b5[1]);
        if (mk & 2u) v0 = 0.f; else if (mk & 1u) v0 = 1.f;
        if (mk & 8u) v1 = 1.f; else if (mk & 4u) v1 = 0.f;
        out[n * 2 + 0] = v0;
        out[n * 2 + 1] = v1;
    }
}

// ---------------------------------------------------------------------------
extern "C" void kernel_launch(void* const* d_in, const int* in_sizes, int n_in,
                              void* d_out, int out_size, void* d_ws, size_t ws_size,
                              hipStream_t stream) {
    const float* x   = (const float*)d_in[0];
    const int*   ei  = (const int*)d_in[1];
    const float* cf  = (const float*)d_in[2];
    const float* cw[4] = {(const float*)d_in[3], (const float*)d_in[5],
                          (const float*)d_in[7], (const float*)d_in[9]};
    const float* cb[4] = {(const float*)d_in[4], (const float*)d_in[6],
                          (const float*)d_in[8], (const float*)d_in[10]};
    const float* gw[5], *gas[5], *gad[5], *gb[5];
    for (int i = 0; i < 5; ++i) {
        gw[i]  = (const float*)d_in[11 + 4 * i];
        gas[i] = (const float*)d_in[12 + 4 * i];
        gad[i] = (const float*)d_in[13 + 4 * i];
        gb[i]  = (const float*)d_in[14 + 4 * i];
    }
    const int N = in_sizes[0] / 10;        // 10000
    const int E = in_sizes[1] / 2;         // 160000
    const int EN = E + N;

    // ---- workspace carve-up ----
    char* base = (char*)d_ws;
    size_t off = 0;
    auto alloc = [&](size_t bytes) -> char* {
        char* p = base + off;
        off = (off + bytes + 255) & ~(size_t)255;
        return p;
    };
    float* cfp   = (float*)alloc((size_t)4 * PSZ * 4);
    float* c1p   = (float*)alloc((size_t)16 * PSZ * 4);
    float* c2p   = (float*)alloc((size_t)32 * PSZ * 4);
    float* c3p   = (float*)alloc((size_t)64 * PSZ * 4);
    float* c4p   = (float*)alloc((size_t)24 * PSZ * 4);
    float* gfeat = (float*)alloc(24 * 4);
    __half* hA16 = (__half*)alloc((size_t)N * 256 * 2);
    __half* hB16 = (__half*)alloc((size_t)N * 256 * 2);
    __half* g    = (__half*)alloc((size_t)N * 2048 * 2);
    float* P     = (float*)alloc((size_t)4 * N * 256 * 4);   // 41 MB partials
    float* esed  = (float*)alloc((size_t)N * 32 * 4);
    float* zinv  = (float*)alloc((size_t)N * 16 * 4);
    float* palpha = (float*)alloc((size_t)EN * 16 * 4);      // fp32 numerators
    float* wesed = (float*)alloc(256 * 32 * 4);
    float* wstack= (float*)alloc((size_t)2048 * 2 * 4);
    unsigned short* bt_hi = (unsigned short*)alloc((size_t)524288 * 2);
    unsigned short* bt_lo = (unsigned short*)alloc((size_t)524288 * 2);
    unsigned* masks = (unsigned*)alloc((size_t)N * 4);
    int* cnt    = (int*)alloc((size_t)N * 4);
    int* indptr = (int*)alloc((size_t)(N + 1) * 4);
    int* cursor = (int*)alloc((size_t)N * 4);
    int* col    = (int*)alloc((size_t)EN * 4);
    (void)ws_size; // ~120 MB

    // ---- CNN (padded layout; single memset zeroes all borders) ----
    hipMemsetAsync(cfp, 0, (size_t)140 * PSZ * 4, stream);
    pad_input<<<(4 * 4096 + 255) / 256, 256, 0, stream>>>(cf, cfp);
    conv3x3_pad<4><<<dim3(4, 16), 256, 0, stream>>>(cfp, cw[0], cb[0], c1p);
    conv3x3_pad<16><<<dim3(4, 32), 256, 0, stream>>>(c1p, cw[1], cb[1], c2p);
    conv3x3_pad<32><<<dim3(4, 64), 256, 0, stream>>>(c2p, cw[2], cb[2], c3p);
    conv3x3_pad<64><<<dim3(4, 24), 256, 0, stream>>>(c3p, cw[3], cb[3], c4p);
    avgpool_c<<<24, 256, 0, stream>>>(c4p, gfeat);

    // ---- h0 (padded to 48, fp16) + masks ----
    build_h0<<<(N + 255) / 256, 256, 0, stream>>>(x, gfeat, hA16, masks, N);

    // ---- CSR by dst (incl self loops) ----
    hipMemsetAsync(cnt, 0, (size_t)N * 4, stream);
    count_dst<<<(EN + 255) / 256, 256, 0, stream>>>(ei, cnt, E, N);
    exscan_single<<<1, 256, 0, stream>>>(cnt, indptr, cursor, N);
    scatter_edges<<<(EN + 255) / 256, 256, 0, stream>>>(ei, cursor, col, E, N);

    // ---- GAT layers ----
    const int Ko[5] = {34, 64, 128, 256, 128};   // true input dims
    const int Kp[5] = {48, 64, 128, 256, 128};   // padded
    const int Hs[5] = {8, 16, 8, 8, 16};
    const int Cs[5] = {64, 128, 256, 128, 2};

    const __half* hin16 = hA16;
    __half* hout16[4]  = {hB16, hA16, hB16, hA16};

    for (int lyr = 0; lyr < 5; ++lyr) {
        int K = Ko[lyr], KP = Kp[lyr], H = Hs[lyr], C = Cs[lyr];
        int KA = H * KP;
        int nprep = ((C > 2) ? C * KA : KA * 2) + KP * 2 * H;
        prep_layer<<<(nprep + 255) / 256, 256, 0, stream>>>(gw[lyr], gas[lyr], gad[lyr],
                                                            bt_hi, bt_lo, wstack, wesed,
                                                            K, KP, H, C);
        esed_kernel<<<(N * 2 * H + 255) / 256, 256, 0, stream>>>(hin16, wesed, esed, N, KP, 2 * H);
        attn_kernel<<<(N * H + 255) / 256, 256, 0, stream>>>(esed, indptr, col,
                                                             palpha, zinv, N, H);
        if (lyr == 0)
            gat_gather<8, 48, 10><<<(N + 9) / 10, 240, 0, stream>>>(hin16, palpha, zinv, indptr, col, g, N);
        else if (lyr == 1)
            gat_gather<16, 64, 8><<<(N + 7) / 8, 256, 0, stream>>>(hin16, palpha, zinv, indptr, col, g, N);
        else if (lyr == 2)
            gat_gather<8, 128, 4><<<(N + 3) / 4, 256, 0, stream>>>(hin16, palpha, zinv, indptr, col, g, N);
        else if (lyr == 3)
            gat_gather<8, 256, 2><<<(N + 1) / 2, 256, 0, stream>>>(hin16, palpha, zinv, indptr, col, g, N);
        else
            gat_gather<16, 128, 4><<<(N + 3) / 4, 256, 0, stream>>>(hin16, palpha, zinv, indptr, col, g, N);

        if (lyr < 4) {
            if (lyr == 0) {            // KA=384, C=64: RT=2, SPLIT=4
                dim3 gg((N + 31) / 32, C / 64, 4);
                gemm_mr<2, 4><<<gg, 64, 0, stream>>>(g, bt_hi, bt_lo, gb[lyr], masks, P, hout16[lyr], N, KA, C);
                reduce_ep<4><<<(N * C + 255) / 256, 256, 0, stream>>>(P, gb[lyr], masks, hout16[lyr], N, C);
            } else if (lyr == 2) {     // KA=2048, C=256: RT=4, SPLIT=4
                dim3 gg((N + 63) / 64, C / 64, 4);
                gemm_mr<4, 4><<<gg, 64, 0, stream>>>(g, bt_hi, bt_lo, gb[lyr], masks, P, hout16[lyr], N, KA, C);
                reduce_ep<4><<<(N * C + 255) / 256, 256, 0, stream>>>(P, gb[lyr], masks, hout16[lyr], N, C);
            } else {                   // KA=1024, C=128: RT=2, SPLIT=4
                dim3 gg((N + 31) / 32, C / 64, 4);
                gemm_mr<2, 4><<<gg, 64, 0, stream>>>(g, bt_hi, bt_lo, gb[lyr], masks, P, hout16[lyr], N, KA, C);
                reduce_ep<4><<<(N * C + 255) / 256, 256, 0, stream>>>(P, gb[lyr], masks, hout16[lyr], N, C);
            }
            hin16 = hout16[lyr];
        } else {
            final5_kernel<<<(N + 3) / 4, 256, 0, stream>>>(g, wstack, gb[4], masks, x,
                                                           (float*)d_out, N, KA);
        }
    }
}

// Round 14
// 804.588 us; speedup vs baseline: 1.1213x; 1.0459x over previous
//
#include <hip/hip_runtime.h>
#include <hip/hip_fp16.h>
#include <math.h>

// ---------------------------------------------------------------------------
// NetGlobGATFix. R14: single-plane fp16 B in the GEMM.
//   - B stored as one fp16 plane (rel err 2^-11 ~ same class as fp16-g
//     storage already in the pipeline); gemm_mr: 1 f16 MFMA per (rt,j),
//     loads/chunk 10 -> 6 in the latency-bound loop.
//   - Everything else identical to R13 (841us).
// ---------------------------------------------------------------------------

#define DEVFN static __device__ __forceinline__

typedef __attribute__((ext_vector_type(8))) _Float16 half8;
typedef __attribute__((ext_vector_type(4))) float f32x4;

DEVFN float selu_f(float v) {
    const float scale = 1.0507009873554805f;
    const float alpha = 1.6732632423543772f;
    return v > 0.f ? scale * v : scale * alpha * (expf(v) - 1.f);
}

DEVFN float lrelu02(float v) { return v > 0.f ? v : 0.2f * v; }

// ---------------- CNN (padded 66x66 layout) ----------------
#define PST 66
#define PSZ (66 * 66)

__global__ void pad_input(const float* __restrict__ cf, float* __restrict__ out) {
    int t = blockIdx.x * blockDim.x + threadIdx.x;
    if (t >= 4 * 4096) return;
    int c = t >> 12, pix = t & 4095;
    int y = pix >> 6, x = pix & 63;
    out[c * PSZ + (y + 1) * PST + (x + 1)] = cf[t];
}

template <int CIN>
__global__ __launch_bounds__(256) void conv3x3_pad(const float* __restrict__ in,
                                                   const float* __restrict__ w,
                                                   const float* __restrict__ b,
                                                   float* __restrict__ out) {
    int x  = threadIdx.x & 63;
    int yg = threadIdx.x >> 6;
    int y0 = blockIdx.x * 16 + yg * 4;
    int co = blockIdx.y;
    float bv = b[co];
    float acc[4] = {bv, bv, bv, bv};
    const float* wp = w + (size_t)co * CIN * 9;
#pragma unroll 4
    for (int ci = 0; ci < CIN; ++ci) {
        const float* ip = in + ci * PSZ + y0 * PST + x;
        float wr[9];
#pragma unroll
        for (int j = 0; j < 9; ++j) wr[j] = wp[ci * 9 + j];
        float r[6][3];
#pragma unroll
        for (int rr = 0; rr < 6; ++rr) {
            r[rr][0] = ip[rr * PST + 0];
            r[rr][1] = ip[rr * PST + 1];
            r[rr][2] = ip[rr * PST + 2];
        }
#pragma unroll
        for (int v = 0; v < 4; ++v)
#pragma unroll
            for (int ky = 0; ky < 3; ++ky)
#pragma unroll
                for (int kx = 0; kx < 3; ++kx)
                    acc[v] += wr[ky * 3 + kx] * r[v + ky][kx];
    }
#pragma unroll
    for (int v = 0; v < 4; ++v)
        out[(size_t)co * PSZ + (y0 + v + 1) * PST + (x + 1)] = selu_f(acc[v]);
}

__global__ void avgpool_c(const float* __restrict__ in, float* __restrict__ gfeat) {
    int c = blockIdx.x;            // 24 blocks
    int t = threadIdx.x;           // 256 threads
    float s = 0.f;
    for (int i = t; i < 4096; i += 256) {
        int y = i >> 6, x = i & 63;
        s += in[c * PSZ + (y + 1) * PST + (x + 1)];
    }
#pragma unroll
    for (int off = 32; off >= 1; off >>= 1) s += __shfl_xor(s, off);
    __shared__ float red[4];
    int wave = t >> 6, lane = t & 63;
    if (lane == 0) red[wave] = s;
    __syncthreads();
    if (t == 0) gfeat[c] = (red[0] + red[1] + red[2] + red[3]) * (1.f / 4096.f);
}

// ---------------- node feature init (padded to 48 ch, fp16) + masks ---------
__global__ void build_h0(const float* __restrict__ x, const float* __restrict__ gfeat,
                         __half* __restrict__ h0f, unsigned* __restrict__ masks, int N) {
    int n = blockIdx.x * blockDim.x + threadIdx.x;
    if (n >= N) return;
    float x0 = x[n * 10 + 0], x1 = x[n * 10 + 1];
    unsigned mk = (x0 == 1.f ? 1u : 0u) | (x0 == 0.f ? 2u : 0u) |
                  (x1 == 0.f ? 4u : 0u) | (x1 == 1.f ? 8u : 0u);
    masks[n] = mk;
    __half* hq = h0f + (size_t)n * 48;
#pragma unroll
    for (int j = 0; j < 48; ++j) {
        float v = (j < 24) ? gfeat[j] : (j < 34 ? x[n * 10 + (j - 24)] : 0.f);
        hq[j] = __float2half(v);
    }
}

// ---------------- CSR build ----------------
__global__ void count_dst(const int* __restrict__ ei, int* __restrict__ cnt, int E, int N) {
    int t = blockIdx.x * blockDim.x + threadIdx.x;
    if (t >= E + N) return;
    int dst = (t < E) ? ei[E + t] : (t - E);
    atomicAdd(&cnt[dst], 1);
}

// exclusive scan; also writes cursor[i] = indptr[i]
__global__ void exscan_single(const int* __restrict__ cnt, int* __restrict__ indptr,
                              int* __restrict__ cursor, int n) {
    __shared__ int sdata[256];
    __shared__ int run_s;
    int tid = threadIdx.x;
    if (tid == 0) { run_s = 0; indptr[0] = 0; }
    __syncthreads();
    for (int base = 0; base < n; base += 256) {
        int i = base + tid;
        int v = (i < n) ? cnt[i] : 0;
        sdata[tid] = v;
        __syncthreads();
        for (int off = 1; off < 256; off <<= 1) {
            int tmp = (tid >= off) ? sdata[tid - off] : 0;
            __syncthreads();
            sdata[tid] += tmp;
            __syncthreads();
        }
        if (i < n) {
            indptr[i + 1] = run_s + sdata[tid];
            cursor[i] = run_s + sdata[tid] - v;
        }
        __syncthreads();
        if (tid == 0) run_s += sdata[255];
        __syncthreads();
    }
}

__global__ void scatter_edges(const int* __restrict__ ei, int* __restrict__ cursor,
                              int* __restrict__ col, int E, int N) {
    int t = blockIdx.x * blockDim.x + threadIdx.x;
    if (t >= E + N) return;
    int src, dst;
    if (t < E) { src = ei[t]; dst = ei[E + t]; }
    else       { src = dst = t - E; }
    int pos = atomicAdd(&cursor[dst], 1);
    col[pos] = src;
}

// ---------------- fused weight prep -----------------------------------------
// Bt plane: single fp16 (err 2^-11, same class as fp16-g storage).
__global__ void prep_layer(const float* __restrict__ W, const float* __restrict__ as,
                           const float* __restrict__ ad,
                           unsigned short* __restrict__ bhi,
                           float* __restrict__ wstack, float* __restrict__ wesed,
                           int K, int Kp, int H, int C) {
    int KA = H * Kp;
    int H2 = 2 * H;
    int nwtb = (C > 2) ? C * KA : 0;
    int nws  = (C == 2) ? KA * 2 : 0;
    int t = blockIdx.x * blockDim.x + threadIdx.x;
    if (t < nwtb) {
        int ka = t % KA;
        int m  = t / KA;
        int h = ka / Kp, k = ka - h * Kp;
        float v = (k < K) ? W[(size_t)k * (H * C) + h * C + m] : 0.f;
        bhi[t] = __half_as_ushort(__float2half(v));
    } else if (t < nwtb + nws) {
        int u = t - nwtb;
        int c = u & 1, r = u >> 1;           // r = h*Kp + k
        int h = r / Kp, k = r - h * Kp;
        wstack[u] = (k < K) ? W[(size_t)k * (H * C) + h * C + c] : 0.f;
    } else if (t < nwtb + nws + Kp * H2) {
        int u = t - nwtb - nws;
        int k = u / H2, o = u - k * H2;
        float s = 0.f;
        if (k < K) {
            int h = (o < H) ? o : o - H;
            const float* av = ((o < H) ? as : ad) + h * C;
            const float* wp = W + (size_t)k * (H * C) + h * C;
            for (int c = 0; c < C; ++c) s += wp[c] * av[c];
        }
        wesed[u] = s;
    }
}

// ---------------- es/ed: esed[n, o] = hin16[n,:] @ wesed[:,o], o < 2H -------
__global__ void esed_kernel(const __half* __restrict__ hin, const float* __restrict__ wesed,
                            float* __restrict__ esed, int N, int Kp, int H2) {
    int t = blockIdx.x * blockDim.x + threadIdx.x;
    if (t >= N * H2) return;
    int n = t / H2, o = t - n * H2;
    const __half2* hp = (const __half2*)(hin + (size_t)n * Kp);
    float s = 0.f;
    for (int k2 = 0; k2 < Kp / 2; ++k2) {
        float2 f = __half22float2(hp[k2]);
        s += f.x * wesed[(2 * k2) * H2 + o] + f.y * wesed[(2 * k2 + 1) * H2 + o];
    }
    esed[t] = s;
}

// ---------------- attention: single pass (softmax shift-invariant) ----------
__global__ void attn_kernel(const float* __restrict__ esed,
                            const int* __restrict__ indptr, const int* __restrict__ col,
                            float* __restrict__ palpha, float* __restrict__ zinv,
                            int N, int H) {
    int t = blockIdx.x * blockDim.x + threadIdx.x;
    if (t >= N * H) return;
    int n = t / H, h = t - n * H;
    int H2 = 2 * H;
    float edv = esed[n * H2 + H + h];
    int beg = indptr[n], end = indptr[n + 1];
    float z = 0.f;
    for (int i = beg; i < end; ++i) {
        float e = lrelu02(esed[col[i] * H2 + h] + edv);
        float p = expf(e);
        palpha[(size_t)i * H + h] = p;
        z += p;
    }
    zinv[t] = (1.f / H) / (z + 1e-16f);
}

// ---------------- gather: g[n, h*KP+k] = zinv * Sum_e p * hin16[src, k] -----
template <int H, int KP, int NPB>
__global__ __launch_bounds__(NPB * KP / 2) void gat_gather(
        const __half* __restrict__ hinf, const float* __restrict__ palpha,
        const float* __restrict__ zinv, const int* __restrict__ indptr,
        const int* __restrict__ col, __half* __restrict__ g, int N) {
    const int TPN = KP / 2;
    int sub = threadIdx.x / TPN;
    int j   = threadIdx.x % TPN;
    int n = blockIdx.x * NPB + sub;
    if (n >= N) return;
    int c0 = j * 2;
    float acc[H][2];
#pragma unroll
    for (int h = 0; h < H; ++h) { acc[h][0] = 0.f; acc[h][1] = 0.f; }
    int beg = indptr[n], end = indptr[n + 1];
    for (int i = beg; i < end; ++i) {
        int src = col[i];
        __half2 hv = *(const __half2*)(hinf + (size_t)src * KP + c0);
        float2 f = __half22float2(hv);
        const float2* ap = (const float2*)(palpha + (size_t)i * H);
#pragma unroll
        for (int h2 = 0; h2 < H / 2; ++h2) {
            float2 aa = ap[h2];
            acc[2 * h2 + 0][0] += aa.x * f.x;
            acc[2 * h2 + 0][1] += aa.x * f.y;
            acc[2 * h2 + 1][0] += aa.y * f.x;
            acc[2 * h2 + 1][1] += aa.y * f.y;
        }
    }
    __half* gp = g + (size_t)n * (H * KP) + c0;
#pragma unroll
    for (int h = 0; h < H; ++h) {
        float zf = zinv[n * H + h];
        *(__half2*)(gp + h * KP) = __floats2half2_rn(acc[h][0] * zf, acc[h][1] * zf);
    }
}

// ---------------- multi-row-tile split-K f16 MFMA GEMM ----------------------
// A fp16 [N x K], Bt fp16 [M x K]. Per (rt,j): 1 f16 MFMA.
template <int RT, int SPLIT>
__global__ __launch_bounds__(64) void gemm_mr(const __half* __restrict__ A,
                                              const unsigned short* __restrict__ Bhi,
                                              const float* __restrict__ bias,
                                              const unsigned* __restrict__ masks,
                                              float* __restrict__ P,
                                              __half* __restrict__ O16,
                                              int N, int K, int M) {
    int lane = threadIdx.x;
    int ln16 = lane & 15;
    int q    = lane >> 4;                 // 0..3 (k-octet)
    int row0 = blockIdx.x * (16 * RT);
    int col0 = blockIdx.y * 64;
    int kb   = (K / SPLIT) * blockIdx.z;
    int ke   = kb + K / SPLIT;

    const __half* ap = A + (size_t)(row0 + ln16) * K + q * 8;
    const unsigned short* bhp = Bhi + (size_t)(col0 + ln16) * K + q * 8;
    const size_t cstep = (size_t)16 * K;

    f32x4 acc[RT][4];
#pragma unroll
    for (int rt = 0; rt < RT; ++rt)
#pragma unroll
        for (int j = 0; j < 4; ++j) acc[rt][j] = (f32x4){0.f, 0.f, 0.f, 0.f};

#pragma unroll 2
    for (int kc = kb; kc < ke; kc += 32) {
        half8 bh[4];
#pragma unroll
        for (int j = 0; j < 4; ++j)
            bh[j] = *(const half8*)(bhp + (size_t)j * cstep + kc);
        half8 a[RT];
#pragma unroll
        for (int rt = 0; rt < RT; ++rt)
            a[rt] = *(const half8*)(ap + (size_t)rt * cstep + kc);
#pragma unroll
        for (int rt = 0; rt < RT; ++rt) {
#pragma unroll
            for (int j = 0; j < 4; ++j)
                acc[rt][j] = __builtin_amdgcn_mfma_f32_16x16x32_f16(a[rt], bh[j], acc[rt][j], 0, 0, 0);
        }
    }

    // C/D layout: col = lane&15, row = (lane>>4)*4 + reg
    if (SPLIT == 1) {
#pragma unroll
        for (int rt = 0; rt < RT; ++rt) {
#pragma unroll
            for (int j = 0; j < 4; ++j) {
                int cc = col0 + j * 16 + ln16;
                float bv = bias[cc];
#pragma unroll
                for (int r = 0; r < 4; ++r) {
                    int rr = row0 + rt * 16 + q * 4 + r;
                    if (rr >= N) continue;
                    float v = selu_f(acc[rt][j][r] + bv);
                    if (cc < 2) {
                        unsigned mk = masks[rr];
                        if (cc == 0) { if (mk & 2u) v = 0.f; else if (mk & 1u) v = 1.f; }
                        else         { if (mk & 8u) v = 1.f; else if (mk & 4u) v = 0.f; }
                    }
                    O16[(size_t)rr * M + cc] = __float2half(v);
                }
            }
        }
    } else {
        float* Pz = P + (size_t)blockIdx.z * N * M;
#pragma unroll
        for (int rt = 0; rt < RT; ++rt) {
#pragma unroll
            for (int j = 0; j < 4; ++j) {
                int cc = col0 + j * 16 + ln16;
#pragma unroll
                for (int r = 0; r < 4; ++r) {
                    int rr = row0 + rt * 16 + q * 4 + r;
                    if (rr >= N) continue;
                    Pz[(size_t)rr * M + cc] = acc[rt][j][r];
                }
            }
        }
    }
}

// ---------------- reduce partials + bias/selu/boundary -> fp16 --------------
template <int SPLIT>
__global__ __launch_bounds__(256) void reduce_ep(const float* __restrict__ P,
                                                 const float* __restrict__ bias,
                                                 const unsigned* __restrict__ masks,
                                                 __half* __restrict__ O16,
                                                 int N, int M) {
    int t = blockIdx.x * 256 + threadIdx.x;
    if (t >= N * M) return;
    int n = t / M, c = t - n * M;
    float v = 0.f;
#pragma unroll
    for (int s = 0; s < SPLIT; ++s) v += P[(size_t)s * N * M + t];
    v = selu_f(v + bias[c]);
    if (c < 2) {
        unsigned mk = masks[n];
        if (c == 0) { if (mk & 2u) v = 0.f; else if (mk & 1u) v = 1.f; }
        else        { if (mk & 8u) v = 1.f; else if (mk & 4u) v = 0.f; }
    }
    O16[t] = __float2half(v);
}

// ---------------- final layer (C=2): out = bfix(x + selu(g @ W5s + b5)) -----
__global__ __launch_bounds__(256) void final5_kernel(const __half* __restrict__ g,
                                                     const float* __restrict__ W5,
                                                     const float* __restrict__ b5,
                                                     const unsigned* __restrict__ masks,
                                                     const float* __restrict__ x,
                                                     float* __restrict__ out,
                                                     int N, int KA) {
    int wave = threadIdx.x >> 6, lane = threadIdx.x & 63;
    int n = blockIdx.x * 4 + wave;
    if (n >= N) return;
    float a0 = 0.f, a1 = 0.f;
    const __half* gp = g + (size_t)n * KA;
    for (int k = lane * 2; k < KA; k += 128) {
        float2 f = __half22float2(*(const __half2*)(gp + k));
        float4 w = *(const float4*)(W5 + (size_t)k * 2);
        a0 += f.x * w.x + f.y * w.z;
        a1 += f.x * w.y + f.y * w.w;
    }
#pragma unroll
    for (int off = 32; off >= 1; off >>= 1) {
        a0 += __shfl_xor(a0, off);
        a1 += __shfl_xor(a1, off);
    }
    if (lane == 0) {
        unsigned mk = masks[n];
        float v0 = x[n * 10 + 0] + selu_f(a0 + b5[0]);
        float v1 = x[n * 10 + 1] + selu_f(a1 + b5[1]);
        if (mk & 2u) v0 = 0.f; else if (mk & 1u) v0 = 1.f;
        if (mk & 8u) v1 = 1.f; else if (mk & 4u) v1 = 0.f;
        out[n * 2 + 0] = v0;
        out[n * 2 + 1] = v1;
    }
}

// ---------------------------------------------------------------------------
extern "C" void kernel_launch(void* const* d_in, const int* in_sizes, int n_in,
                              void* d_out, int out_size, void* d_ws, size_t ws_size,
                              hipStream_t stream) {
    const float* x   = (const float*)d_in[0];
    const int*   ei  = (const int*)d_in[1];
    const float* cf  = (const float*)d_in[2];
    const float* cw[4] = {(const float*)d_in[3], (const float*)d_in[5],
                          (const float*)d_in[7], (const float*)d_in[9]};
    const float* cb[4] = {(const float*)d_in[4], (const float*)d_in[6],
                          (const float*)d_in[8], (const float*)d_in[10]};
    const float* gw[5], *gas[5], *gad[5], *gb[5];
    for (int i = 0; i < 5; ++i) {
        gw[i]  = (const float*)d_in[11 + 4 * i];
        gas[i] = (const float*)d_in[12 + 4 * i];
        gad[i] = (const float*)d_in[13 + 4 * i];
        gb[i]  = (const float*)d_in[14 + 4 * i];
    }
    const int N = in_sizes[0] / 10;        // 10000
    const int E = in_sizes[1] / 2;         // 160000
    const int EN = E + N;

    // ---- workspace carve-up ----
    char* base = (char*)d_ws;
    size_t off = 0;
    auto alloc = [&](size_t bytes) -> char* {
        char* p = base + off;
        off = (off + bytes + 255) & ~(size_t)255;
        return p;
    };
    float* cfp   = (float*)alloc((size_t)4 * PSZ * 4);
    float* c1p   = (float*)alloc((size_t)16 * PSZ * 4);
    float* c2p   = (float*)alloc((size_t)32 * PSZ * 4);
    float* c3p   = (float*)alloc((size_t)64 * PSZ * 4);
    float* c4p   = (float*)alloc((size_t)24 * PSZ * 4);
    float* gfeat = (float*)alloc(24 * 4);
    __half* hA16 = (__half*)alloc((size_t)N * 256 * 2);
    __half* hB16 = (__half*)alloc((size_t)N * 256 * 2);
    __half* g    = (__half*)alloc((size_t)N * 2048 * 2);
    float* P     = (float*)alloc((size_t)4 * N * 256 * 4);   // 41 MB partials
    float* esed  = (float*)alloc((size_t)N * 32 * 4);
    float* zinv  = (float*)alloc((size_t)N * 16 * 4);
    float* palpha = (float*)alloc((size_t)EN * 16 * 4);      // fp32 numerators
    float* wesed = (float*)alloc(256 * 32 * 4);
    float* wstack= (float*)alloc((size_t)2048 * 2 * 4);
    unsigned short* bt_hi = (unsigned short*)alloc((size_t)524288 * 2);
    unsigned* masks = (unsigned*)alloc((size_t)N * 4);
    int* cnt    = (int*)alloc((size_t)N * 4);
    int* indptr = (int*)alloc((size_t)(N + 1) * 4);
    int* cursor = (int*)alloc((size_t)N * 4);
    int* col    = (int*)alloc((size_t)EN * 4);
    (void)ws_size; // ~119 MB

    // ---- CNN (padded layout; single memset zeroes all borders) ----
    hipMemsetAsync(cfp, 0, (size_t)140 * PSZ * 4, stream);
    pad_input<<<(4 * 4096 + 255) / 256, 256, 0, stream>>>(cf, cfp);
    conv3x3_pad<4><<<dim3(4, 16), 256, 0, stream>>>(cfp, cw[0], cb[0], c1p);
    conv3x3_pad<16><<<dim3(4, 32), 256, 0, stream>>>(c1p, cw[1], cb[1], c2p);
    conv3x3_pad<32><<<dim3(4, 64), 256, 0, stream>>>(c2p, cw[2], cb[2], c3p);
    conv3x3_pad<64><<<dim3(4, 24), 256, 0, stream>>>(c3p, cw[3], cb[3], c4p);
    avgpool_c<<<24, 256, 0, stream>>>(c4p, gfeat);

    // ---- h0 (padded to 48, fp16) + masks ----
    build_h0<<<(N + 255) / 256, 256, 0, stream>>>(x, gfeat, hA16, masks, N);

    // ---- CSR by dst (incl self loops) ----
    hipMemsetAsync(cnt, 0, (size_t)N * 4, stream);
    count_dst<<<(EN + 255) / 256, 256, 0, stream>>>(ei, cnt, E, N);
    exscan_single<<<1, 256, 0, stream>>>(cnt, indptr, cursor, N);
    scatter_edges<<<(EN + 255) / 256, 256, 0, stream>>>(ei, cursor, col, E, N);

    // ---- GAT layers ----
    const int Ko[5] = {34, 64, 128, 256, 128};   // true input dims
    const int Kp[5] = {48, 64, 128, 256, 128};   // padded
    const int Hs[5] = {8, 16, 8, 8, 16};
    const int Cs[5] = {64, 128, 256, 128, 2};

    const __half* hin16 = hA16;
    __half* hout16[4]  = {hB16, hA16, hB16, hA16};

    for (int lyr = 0; lyr < 5; ++lyr) {
        int K = Ko[lyr], KP = Kp[lyr], H = Hs[lyr], C = Cs[lyr];
        int KA = H * KP;
        int nprep = ((C > 2) ? C * KA : KA * 2) + KP * 2 * H;
        prep_layer<<<(nprep + 255) / 256, 256, 0, stream>>>(gw[lyr], gas[lyr], gad[lyr],
                                                            bt_hi, wstack, wesed,
                                                            K, KP, H, C);
        esed_kernel<<<(N * 2 * H + 255) / 256, 256, 0, stream>>>(hin16, wesed, esed, N, KP, 2 * H);
        attn_kernel<<<(N * H + 255) / 256, 256, 0, stream>>>(esed, indptr, col,
                                                             palpha, zinv, N, H);
        if (lyr == 0)
            gat_gather<8, 48, 10><<<(N + 9) / 10, 240, 0, stream>>>(hin16, palpha, zinv, indptr, col, g, N);
        else if (lyr == 1)
            gat_gather<16, 64, 8><<<(N + 7) / 8, 256, 0, stream>>>(hin16, palpha, zinv, indptr, col, g, N);
        else if (lyr == 2)
            gat_gather<8, 128, 4><<<(N + 3) / 4, 256, 0, stream>>>(hin16, palpha, zinv, indptr, col, g, N);
        else if (lyr == 3)
            gat_gather<8, 256, 2><<<(N + 1) / 2, 256, 0, stream>>>(hin16, palpha, zinv, indptr, col, g, N);
        else
            gat_gather<16, 128, 4><<<(N + 3) / 4, 256, 0, stream>>>(hin16, palpha, zinv, indptr, col, g, N);

        if (lyr < 4) {
            if (lyr == 0) {            // KA=384, C=64: RT=2, SPLIT=4
                dim3 gg((N + 31) / 32, C / 64, 4);
                gemm_mr<2, 4><<<gg, 64, 0, stream>>>(g, bt_hi, gb[lyr], masks, P, hout16[lyr], N, KA, C);
                reduce_ep<4><<<(N * C + 255) / 256, 256, 0, stream>>>(P, gb[lyr], masks, hout16[lyr], N, C);
            } else if (lyr == 2) {     // KA=1024, C=256: RT=4, SPLIT=4
                dim3 gg((N + 63) / 64, C / 64, 4);
                gemm_mr<4, 4><<<gg, 64, 0, stream>>>(g, bt_hi, gb[lyr], masks, P, hout16[lyr], N, KA, C);
                reduce_ep<4><<<(N * C + 255) / 256, 256, 0, stream>>>(P, gb[lyr], masks, hout16[lyr], N, C);
            } else {                   // KA=1024/2048, C=128: RT=2, SPLIT=4
                dim3 gg((N + 31) / 32, C / 64, 4);
                gemm_mr<2, 4><<<gg, 64, 0, stream>>>(g, bt_hi, gb[lyr], masks, P, hout16[lyr], N, KA, C);
                reduce_ep<4><<<(N * C + 255) / 256, 256, 0, stream>>>(P, gb[lyr], masks, hout16[lyr], N, C);
            }
            hin16 = hout16[lyr];
        } else {
            final5_kernel<<<(N + 3) / 4, 256, 0, stream>>>(g, wstack, gb[4], masks, x,
                                                           (float*)d_out, N, KA);
        }
    }
}

// Round 15
// 769.888 us; speedup vs baseline: 1.1718x; 1.0451x over previous
//
#include <hip/hip_runtime.h>
#include <hip/hip_fp16.h>
#include <math.h>

// ---------------------------------------------------------------------------
// NetGlobGATFix. R15: tail fixes on prep + scan.
//   - prep_layer: k-major mapping -> coalesced W reads (writes strided,
//     posted). Was 47us memory-divergence-bound at 43 GB/s.
//   - exscan_single (47us, single-block serial) -> 3-kernel parallel scan.
//   - Everything else identical to R14 (804us).
// ---------------------------------------------------------------------------

#define DEVFN static __device__ __forceinline__

typedef __attribute__((ext_vector_type(8))) _Float16 half8;
typedef __attribute__((ext_vector_type(4))) float f32x4;

DEVFN float selu_f(float v) {
    const float scale = 1.0507009873554805f;
    const float alpha = 1.6732632423543772f;
    return v > 0.f ? scale * v : scale * alpha * (expf(v) - 1.f);
}

DEVFN float lrelu02(float v) { return v > 0.f ? v : 0.2f * v; }

// ---------------- CNN (padded 66x66 layout) ----------------
#define PST 66
#define PSZ (66 * 66)

__global__ void pad_input(const float* __restrict__ cf, float* __restrict__ out) {
    int t = blockIdx.x * blockDim.x + threadIdx.x;
    if (t >= 4 * 4096) return;
    int c = t >> 12, pix = t & 4095;
    int y = pix >> 6, x = pix & 63;
    out[c * PSZ + (y + 1) * PST + (x + 1)] = cf[t];
}

template <int CIN>
__global__ __launch_bounds__(256) void conv3x3_pad(const float* __restrict__ in,
                                                   const float* __restrict__ w,
                                                   const float* __restrict__ b,
                                                   float* __restrict__ out) {
    int x  = threadIdx.x & 63;
    int yg = threadIdx.x >> 6;
    int y0 = blockIdx.x * 16 + yg * 4;
    int co = blockIdx.y;
    float bv = b[co];
    float acc[4] = {bv, bv, bv, bv};
    const float* wp = w + (size_t)co * CIN * 9;
#pragma unroll 4
    for (int ci = 0; ci < CIN; ++ci) {
        const float* ip = in + ci * PSZ + y0 * PST + x;
        float wr[9];
#pragma unroll
        for (int j = 0; j < 9; ++j) wr[j] = wp[ci * 9 + j];
        float r[6][3];
#pragma unroll
        for (int rr = 0; rr < 6; ++rr) {
            r[rr][0] = ip[rr * PST + 0];
            r[rr][1] = ip[rr * PST + 1];
            r[rr][2] = ip[rr * PST + 2];
        }
#pragma unroll
        for (int v = 0; v < 4; ++v)
#pragma unroll
            for (int ky = 0; ky < 3; ++ky)
#pragma unroll
                for (int kx = 0; kx < 3; ++kx)
                    acc[v] += wr[ky * 3 + kx] * r[v + ky][kx];
    }
#pragma unroll
    for (int v = 0; v < 4; ++v)
        out[(size_t)co * PSZ + (y0 + v + 1) * PST + (x + 1)] = selu_f(acc[v]);
}

__global__ void avgpool_c(const float* __restrict__ in, float* __restrict__ gfeat) {
    int c = blockIdx.x;            // 24 blocks
    int t = threadIdx.x;           // 256 threads
    float s = 0.f;
    for (int i = t; i < 4096; i += 256) {
        int y = i >> 6, x = i & 63;
        s += in[c * PSZ + (y + 1) * PST + (x + 1)];
    }
#pragma unroll
    for (int off = 32; off >= 1; off >>= 1) s += __shfl_xor(s, off);
    __shared__ float red[4];
    int wave = t >> 6, lane = t & 63;
    if (lane == 0) red[wave] = s;
    __syncthreads();
    if (t == 0) gfeat[c] = (red[0] + red[1] + red[2] + red[3]) * (1.f / 4096.f);
}

// ---------------- node feature init (padded to 48 ch, fp16) + masks ---------
__global__ void build_h0(const float* __restrict__ x, const float* __restrict__ gfeat,
                         __half* __restrict__ h0f, unsigned* __restrict__ masks, int N) {
    int n = blockIdx.x * blockDim.x + threadIdx.x;
    if (n >= N) return;
    float x0 = x[n * 10 + 0], x1 = x[n * 10 + 1];
    unsigned mk = (x0 == 1.f ? 1u : 0u) | (x0 == 0.f ? 2u : 0u) |
                  (x1 == 0.f ? 4u : 0u) | (x1 == 1.f ? 8u : 0u);
    masks[n] = mk;
    __half* hq = h0f + (size_t)n * 48;
#pragma unroll
    for (int j = 0; j < 48; ++j) {
        float v = (j < 24) ? gfeat[j] : (j < 34 ? x[n * 10 + (j - 24)] : 0.f);
        hq[j] = __float2half(v);
    }
}

// ---------------- CSR build (parallel scan) ----------------
__global__ void count_dst(const int* __restrict__ ei, int* __restrict__ cnt, int E, int N) {
    int t = blockIdx.x * blockDim.x + threadIdx.x;
    if (t >= E + N) return;
    int dst = (t < E) ? ei[E + t] : (t - E);
    atomicAdd(&cnt[dst], 1);
}

// per-block exclusive scan + block sums
__global__ void scan_blocks(const int* __restrict__ cnt, int* __restrict__ pref,
                            int* __restrict__ bsums, int n) {
    __shared__ int sdata[256];
    int i = blockIdx.x * 256 + threadIdx.x;
    int v = (i < n) ? cnt[i] : 0;
    sdata[threadIdx.x] = v;
    __syncthreads();
    for (int off = 1; off < 256; off <<= 1) {
        int tmp = (threadIdx.x >= off) ? sdata[threadIdx.x - off] : 0;
        __syncthreads();
        sdata[threadIdx.x] += tmp;
        __syncthreads();
    }
    if (i < n) pref[i] = sdata[threadIdx.x] - v;
    if (threadIdx.x == 255) bsums[blockIdx.x] = sdata[255];
}

// single-wave exclusive scan of block sums (nb <= 64)
__global__ void scan_sums(int* __restrict__ bsums, int nb) {
    int tid = threadIdx.x;                 // 64
    int orig = (tid < nb) ? bsums[tid] : 0;
    int v = orig;
#pragma unroll
    for (int off = 1; off < 64; off <<= 1) {
        int u = __shfl_up(v, off);
        if (tid >= off) v += u;
    }
    if (tid < nb) bsums[tid] = v - orig;
}

__global__ void scan_apply(const int* __restrict__ pref, const int* __restrict__ bsums,
                           int* __restrict__ indptr, int* __restrict__ cursor,
                           int n, int total) {
    int i = blockIdx.x * 256 + threadIdx.x;
    if (i == 0) indptr[n] = total;
    if (i >= n) return;
    int e = bsums[blockIdx.x] + pref[i];
    indptr[i] = e;
    cursor[i] = e;
}

__global__ void scatter_edges(const int* __restrict__ ei, int* __restrict__ cursor,
                              int* __restrict__ col, int E, int N) {
    int t = blockIdx.x * blockDim.x + threadIdx.x;
    if (t >= E + N) return;
    int src, dst;
    if (t < E) { src = ei[t]; dst = ei[E + t]; }
    else       { src = dst = t - E; }
    int pos = atomicAdd(&cursor[dst], 1);
    col[pos] = src;
}

// ---------------- fused weight prep (coalesced W reads) ---------------------
// Bt section: t is k-major over [Kp x H x C] -> consecutive threads read
// consecutive W elements; strided (posted) writes to bhi[m*KA + h*Kp + k].
__global__ void prep_layer(const float* __restrict__ W, const float* __restrict__ as,
                           const float* __restrict__ ad,
                           unsigned short* __restrict__ bhi,
                           float* __restrict__ wstack, float* __restrict__ wesed,
                           int K, int Kp, int H, int C) {
    int KA = H * Kp;
    int H2 = 2 * H;
    int HC = H * C;
    int nwtb = (C > 2) ? Kp * HC : 0;
    int nws  = (C == 2) ? KA * 2 : 0;
    int t = blockIdx.x * blockDim.x + threadIdx.x;
    if (t < nwtb) {
        int k = t / HC, rem = t - k * HC;
        int h = rem / C, m = rem - h * C;
        float v = (k < K) ? W[(size_t)k * HC + rem] : 0.f;   // coalesced read
        bhi[(size_t)m * KA + h * Kp + k] = __half_as_ushort(__float2half(v));
    } else if (t < nwtb + nws) {
        int u = t - nwtb;
        int c = u & 1, r = u >> 1;           // r = h*Kp + k
        int h = r / Kp, k = r - h * Kp;
        wstack[u] = (k < K) ? W[(size_t)k * HC + h * C + c] : 0.f;
    } else if (t < nwtb + nws + Kp * H2) {
        int u = t - nwtb - nws;
        int k = u / H2, o = u - k * H2;
        float s = 0.f;
        if (k < K) {
            int h = (o < H) ? o : o - H;
            const float* av = ((o < H) ? as : ad) + h * C;
            const float* wp = W + (size_t)k * HC + h * C;
            for (int c = 0; c < C; ++c) s += wp[c] * av[c];
        }
        wesed[u] = s;
    }
}

// ---------------- es/ed: esed[n, o] = hin16[n,:] @ wesed[:,o], o < 2H -------
__global__ void esed_kernel(const __half* __restrict__ hin, const float* __restrict__ wesed,
                            float* __restrict__ esed, int N, int Kp, int H2) {
    int t = blockIdx.x * blockDim.x + threadIdx.x;
    if (t >= N * H2) return;
    int n = t / H2, o = t - n * H2;
    const __half2* hp = (const __half2*)(hin + (size_t)n * Kp);
    float s = 0.f;
    for (int k2 = 0; k2 < Kp / 2; ++k2) {
        float2 f = __half22float2(hp[k2]);
        s += f.x * wesed[(2 * k2) * H2 + o] + f.y * wesed[(2 * k2 + 1) * H2 + o];
    }
    esed[t] = s;
}

// ---------------- attention: single pass (softmax shift-invariant) ----------
__global__ void attn_kernel(const float* __restrict__ esed,
                            const int* __restrict__ indptr, const int* __restrict__ col,
                            float* __restrict__ palpha, float* __restrict__ zinv,
                            int N, int H) {
    int t = blockIdx.x * blockDim.x + threadIdx.x;
    if (t >= N * H) return;
    int n = t / H, h = t - n * H;
    int H2 = 2 * H;
    float edv = esed[n * H2 + H + h];
    int beg = indptr[n], end = indptr[n + 1];
    float z = 0.f;
    for (int i = beg; i < end; ++i) {
        float e = lrelu02(esed[col[i] * H2 + h] + edv);
        float p = expf(e);
        palpha[(size_t)i * H + h] = p;
        z += p;
    }
    zinv[t] = (1.f / H) / (z + 1e-16f);
}

// ---------------- gather: g[n, h*KP+k] = zinv * Sum_e p * hin16[src, k] -----
template <int H, int KP, int NPB>
__global__ __launch_bounds__(NPB * KP / 2) void gat_gather(
        const __half* __restrict__ hinf, const float* __restrict__ palpha,
        const float* __restrict__ zinv, const int* __restrict__ indptr,
        const int* __restrict__ col, __half* __restrict__ g, int N) {
    const int TPN = KP / 2;
    int sub = threadIdx.x / TPN;
    int j   = threadIdx.x % TPN;
    int n = blockIdx.x * NPB + sub;
    if (n >= N) return;
    int c0 = j * 2;
    float acc[H][2];
#pragma unroll
    for (int h = 0; h < H; ++h) { acc[h][0] = 0.f; acc[h][1] = 0.f; }
    int beg = indptr[n], end = indptr[n + 1];
    for (int i = beg; i < end; ++i) {
        int src = col[i];
        __half2 hv = *(const __half2*)(hinf + (size_t)src * KP + c0);
        float2 f = __half22float2(hv);
        const float2* ap = (const float2*)(palpha + (size_t)i * H);
#pragma unroll
        for (int h2 = 0; h2 < H / 2; ++h2) {
            float2 aa = ap[h2];
            acc[2 * h2 + 0][0] += aa.x * f.x;
            acc[2 * h2 + 0][1] += aa.x * f.y;
            acc[2 * h2 + 1][0] += aa.y * f.x;
            acc[2 * h2 + 1][1] += aa.y * f.y;
        }
    }
    __half* gp = g + (size_t)n * (H * KP) + c0;
#pragma unroll
    for (int h = 0; h < H; ++h) {
        float zf = zinv[n * H + h];
        *(__half2*)(gp + h * KP) = __floats2half2_rn(acc[h][0] * zf, acc[h][1] * zf);
    }
}

// ---------------- multi-row-tile split-K f16 MFMA GEMM ----------------------
template <int RT, int SPLIT>
__global__ __launch_bounds__(64) void gemm_mr(const __half* __restrict__ A,
                                              const unsigned short* __restrict__ Bhi,
                                              const float* __restrict__ bias,
                                              const unsigned* __restrict__ masks,
                                              float* __restrict__ P,
                                              __half* __restrict__ O16,
                                              int N, int K, int M) {
    int lane = threadIdx.x;
    int ln16 = lane & 15;
    int q    = lane >> 4;                 // 0..3 (k-octet)
    int row0 = blockIdx.x * (16 * RT);
    int col0 = blockIdx.y * 64;
    int kb   = (K / SPLIT) * blockIdx.z;
    int ke   = kb + K / SPLIT;

    const __half* ap = A + (size_t)(row0 + ln16) * K + q * 8;
    const unsigned short* bhp = Bhi + (size_t)(col0 + ln16) * K + q * 8;
    const size_t cstep = (size_t)16 * K;

    f32x4 acc[RT][4];
#pragma unroll
    for (int rt = 0; rt < RT; ++rt)
#pragma unroll
        for (int j = 0; j < 4; ++j) acc[rt][j] = (f32x4){0.f, 0.f, 0.f, 0.f};

#pragma unroll 2
    for (int kc = kb; kc < ke; kc += 32) {
        half8 bh[4];
#pragma unroll
        for (int j = 0; j < 4; ++j)
            bh[j] = *(const half8*)(bhp + (size_t)j * cstep + kc);
        half8 a[RT];
#pragma unroll
        for (int rt = 0; rt < RT; ++rt)
            a[rt] = *(const half8*)(ap + (size_t)rt * cstep + kc);
#pragma unroll
        for (int rt = 0; rt < RT; ++rt) {
#pragma unroll
            for (int j = 0; j < 4; ++j)
                acc[rt][j] = __builtin_amdgcn_mfma_f32_16x16x32_f16(a[rt], bh[j], acc[rt][j], 0, 0, 0);
        }
    }

    // C/D layout: col = lane&15, row = (lane>>4)*4 + reg
    if (SPLIT == 1) {
#pragma unroll
        for (int rt = 0; rt < RT; ++rt) {
#pragma unroll
            for (int j = 0; j < 4; ++j) {
                int cc = col0 + j * 16 + ln16;
                float bv = bias[cc];
#pragma unroll
                for (int r = 0; r < 4; ++r) {
                    int rr = row0 + rt * 16 + q * 4 + r;
                    if (rr >= N) continue;
                    float v = selu_f(acc[rt][j][r] + bv);
                    if (cc < 2) {
                        unsigned mk = masks[rr];
                        if (cc == 0) { if (mk & 2u) v = 0.f; else if (mk & 1u) v = 1.f; }
                        else         { if (mk & 8u) v = 1.f; else if (mk & 4u) v = 0.f; }
                    }
                    O16[(size_t)rr * M + cc] = __float2half(v);
                }
            }
        }
    } else {
        float* Pz = P + (size_t)blockIdx.z * N * M;
#pragma unroll
        for (int rt = 0; rt < RT; ++rt) {
#pragma unroll
            for (int j = 0; j < 4; ++j) {
                int cc = col0 + j * 16 + ln16;
#pragma unroll
                for (int r = 0; r < 4; ++r) {
                    int rr = row0 + rt * 16 + q * 4 + r;
                    if (rr >= N) continue;
                    Pz[(size_t)rr * M + cc] = acc[rt][j][r];
                }
            }
        }
    }
}

// ---------------- reduce partials + bias/selu/boundary -> fp16 --------------
template <int SPLIT>
__global__ __launch_bounds__(256) void reduce_ep(const float* __restrict__ P,
                                                 const float* __restrict__ bias,
                                                 const unsigned* __restrict__ masks,
                                                 __half* __restrict__ O16,
                                                 int N, int M) {
    int t = blockIdx.x * 256 + threadIdx.x;
    if (t >= N * M) return;
    int n = t / M, c = t - n * M;
    float v = 0.f;
#pragma unroll
    for (int s = 0; s < SPLIT; ++s) v += P[(size_t)s * N * M + t];
    v = selu_f(v + bias[c]);
    if (c < 2) {
        unsigned mk = masks[n];
        if (c == 0) { if (mk & 2u) v = 0.f; else if (mk & 1u) v = 1.f; }
        else        { if (mk & 8u) v = 1.f; else if (mk & 4u) v = 0.f; }
    }
    O16[t] = __float2half(v);
}

// ---------------- final layer (C=2): out = bfix(x + selu(g @ W5s + b5)) -----
__global__ __launch_bounds__(256) void final5_kernel(const __half* __restrict__ g,
                                                     const float* __restrict__ W5,
                                                     const float* __restrict__ b5,
                                                     const unsigned* __restrict__ masks,
                                                     const float* __restrict__ x,
                                                     float* __restrict__ out,
                                                     int N, int KA) {
    int wave = threadIdx.x >> 6, lane = threadIdx.x & 63;
    int n = blockIdx.x * 4 + wave;
    if (n >= N) return;
    float a0 = 0.f, a1 = 0.f;
    const __half* gp = g + (size_t)n * KA;
    for (int k = lane * 2; k < KA; k += 128) {
        float2 f = __half22float2(*(const __half2*)(gp + k));
        float4 w = *(const float4*)(W5 + (size_t)k * 2);
        a0 += f.x * w.x + f.y * w.z;
        a1 += f.x * w.y + f.y * w.w;
    }
#pragma unroll
    for (int off = 32; off >= 1; off >>= 1) {
        a0 += __shfl_xor(a0, off);
        a1 += __shfl_xor(a1, off);
    }
    if (lane == 0) {
        unsigned mk = masks[n];
        float v0 = x[n * 10 + 0] + selu_f(a0 + b5[0]);
        float v1 = x[n * 10 + 1] + selu_f(a1 + b5[1]);
        if (mk & 2u) v0 = 0.f; else if (mk & 1u) v0 = 1.f;
        if (mk & 8u) v1 = 1.f; else if (mk & 4u) v1 = 0.f;
        out[n * 2 + 0] = v0;
        out[n * 2 + 1] = v1;
    }
}

// ---------------------------------------------------------------------------
extern "C" void kernel_launch(void* const* d_in, const int* in_sizes, int n_in,
                              void* d_out, int out_size, void* d_ws, size_t ws_size,
                              hipStream_t stream) {
    const float* x   = (const float*)d_in[0];
    const int*   ei  = (const int*)d_in[1];
    const float* cf  = (const float*)d_in[2];
    const float* cw[4] = {(const float*)d_in[3], (const float*)d_in[5],
                          (const float*)d_in[7], (const float*)d_in[9]};
    const float* cb[4] = {(const float*)d_in[4], (const float*)d_in[6],
                          (const float*)d_in[8], (const float*)d_in[10]};
    const float* gw[5], *gas[5], *gad[5], *gb[5];
    for (int i = 0; i < 5; ++i) {
        gw[i]  = (const float*)d_in[11 + 4 * i];
        gas[i] = (const float*)d_in[12 + 4 * i];
        gad[i] = (const float*)d_in[13 + 4 * i];
        gb[i]  = (const float*)d_in[14 + 4 * i];
    }
    const int N = in_sizes[0] / 10;        // 10000
    const int E = in_sizes[1] / 2;         // 160000
    const int EN = E + N;
    const int NB = (N + 255) / 256;        // scan blocks (40)

    // ---- workspace carve-up ----
    char* base = (char*)d_ws;
    size_t off = 0;
    auto alloc = [&](size_t bytes) -> char* {
        char* p = base + off;
        off = (off + bytes + 255) & ~(size_t)255;
        return p;
    };
    float* cfp   = (float*)alloc((size_t)4 * PSZ * 4);
    float* c1p   = (float*)alloc((size_t)16 * PSZ * 4);
    float* c2p   = (float*)alloc((size_t)32 * PSZ * 4);
    float* c3p   = (float*)alloc((size_t)64 * PSZ * 4);
    float* c4p   = (float*)alloc((size_t)24 * PSZ * 4);
    float* gfeat = (float*)alloc(24 * 4);
    __half* hA16 = (__half*)alloc((size_t)N * 256 * 2);
    __half* hB16 = (__half*)alloc((size_t)N * 256 * 2);
    __half* g    = (__half*)alloc((size_t)N * 2048 * 2);
    float* P     = (float*)alloc((size_t)4 * N * 256 * 4);   // 41 MB partials
    float* esed  = (float*)alloc((size_t)N * 32 * 4);
    float* zinv  = (float*)alloc((size_t)N * 16 * 4);
    float* palpha = (float*)alloc((size_t)EN * 16 * 4);      // fp32 numerators
    float* wesed = (float*)alloc(256 * 32 * 4);
    float* wstack= (float*)alloc((size_t)2048 * 2 * 4);
    unsigned short* bt_hi = (unsigned short*)alloc((size_t)524288 * 2);
    unsigned* masks = (unsigned*)alloc((size_t)N * 4);
    int* cnt    = (int*)alloc((size_t)N * 4);
    int* pref   = (int*)alloc((size_t)N * 4);
    int* bsums  = (int*)alloc(64 * 4);
    int* indptr = (int*)alloc((size_t)(N + 1) * 4);
    int* cursor = (int*)alloc((size_t)N * 4);
    int* col    = (int*)alloc((size_t)EN * 4);
    (void)ws_size; // ~119 MB

    // ---- CNN (padded layout; single memset zeroes all borders) ----
    hipMemsetAsync(cfp, 0, (size_t)140 * PSZ * 4, stream);
    pad_input<<<(4 * 4096 + 255) / 256, 256, 0, stream>>>(cf, cfp);
    conv3x3_pad<4><<<dim3(4, 16), 256, 0, stream>>>(cfp, cw[0], cb[0], c1p);
    conv3x3_pad<16><<<dim3(4, 32), 256, 0, stream>>>(c1p, cw[1], cb[1], c2p);
    conv3x3_pad<32><<<dim3(4, 64), 256, 0, stream>>>(c2p, cw[2], cb[2], c3p);
    conv3x3_pad<64><<<dim3(4, 24), 256, 0, stream>>>(c3p, cw[3], cb[3], c4p);
    avgpool_c<<<24, 256, 0, stream>>>(c4p, gfeat);

    // ---- h0 (padded to 48, fp16) + masks ----
    build_h0<<<(N + 255) / 256, 256, 0, stream>>>(x, gfeat, hA16, masks, N);

    // ---- CSR by dst (incl self loops), parallel scan ----
    hipMemsetAsync(cnt, 0, (size_t)N * 4, stream);
    count_dst<<<(EN + 255) / 256, 256, 0, stream>>>(ei, cnt, E, N);
    scan_blocks<<<NB, 256, 0, stream>>>(cnt, pref, bsums, N);
    scan_sums<<<1, 64, 0, stream>>>(bsums, NB);
    scan_apply<<<NB, 256, 0, stream>>>(pref, bsums, indptr, cursor, N, EN);
    scatter_edges<<<(EN + 255) / 256, 256, 0, stream>>>(ei, cursor, col, E, N);

    // ---- GAT layers ----
    const int Ko[5] = {34, 64, 128, 256, 128};   // true input dims
    const int Kp[5] = {48, 64, 128, 256, 128};   // padded
    const int Hs[5] = {8, 16, 8, 8, 16};
    const int Cs[5] = {64, 128, 256, 128, 2};

    const __half* hin16 = hA16;
    __half* hout16[4]  = {hB16, hA16, hB16, hA16};

    for (int lyr = 0; lyr < 5; ++lyr) {
        int K = Ko[lyr], KP = Kp[lyr], H = Hs[lyr], C = Cs[lyr];
        int KA = H * KP;
        int nprep = ((C > 2) ? KP * H * C : KA * 2) + KP * 2 * H;
        prep_layer<<<(nprep + 255) / 256, 256, 0, stream>>>(gw[lyr], gas[lyr], gad[lyr],
                                                            bt_hi, wstack, wesed,
                                                            K, KP, H, C);
        esed_kernel<<<(N * 2 * H + 255) / 256, 256, 0, stream>>>(hin16, wesed, esed, N, KP, 2 * H);
        attn_kernel<<<(N * H + 255) / 256, 256, 0, stream>>>(esed, indptr, col,
                                                             palpha, zinv, N, H);
        if (lyr == 0)
            gat_gather<8, 48, 10><<<(N + 9) / 10, 240, 0, stream>>>(hin16, palpha, zinv, indptr, col, g, N);
        else if (lyr == 1)
            gat_gather<16, 64, 8><<<(N + 7) / 8, 256, 0, stream>>>(hin16, palpha, zinv, indptr, col, g, N);
        else if (lyr == 2)
            gat_gather<8, 128, 4><<<(N + 3) / 4, 256, 0, stream>>>(hin16, palpha, zinv, indptr, col, g, N);
        else if (lyr == 3)
            gat_gather<8, 256, 2><<<(N + 1) / 2, 256, 0, stream>>>(hin16, palpha, zinv, indptr, col, g, N);
        else
            gat_gather<16, 128, 4><<<(N + 3) / 4, 256, 0, stream>>>(hin16, palpha, zinv, indptr, col, g, N);

        if (lyr < 4) {
            if (lyr == 0) {            // KA=384, C=64: RT=2, SPLIT=4
                dim3 gg((N + 31) / 32, C / 64, 4);
                gemm_mr<2, 4><<<gg, 64, 0, stream>>>(g, bt_hi, gb[lyr], masks, P, hout16[lyr], N, KA, C);
                reduce_ep<4><<<(N * C + 255) / 256, 256, 0, stream>>>(P, gb[lyr], masks, hout16[lyr], N, C);
            } else if (lyr == 2) {     // KA=1024, C=256: RT=4, SPLIT=4
                dim3 gg((N + 63) / 64, C / 64, 4);
                gemm_mr<4, 4><<<gg, 64, 0, stream>>>(g, bt_hi, gb[lyr], masks, P, hout16[lyr], N, KA, C);
                reduce_ep<4><<<(N * C + 255) / 256, 256, 0, stream>>>(P, gb[lyr], masks, hout16[lyr], N, C);
            } else {                   // KA=1024/2048, C=128: RT=2, SPLIT=4
                dim3 gg((N + 31) / 32, C / 64, 4);
                gemm_mr<2, 4><<<gg, 64, 0, stream>>>(g, bt_hi, gb[lyr], masks, P, hout16[lyr], N, KA, C);
                reduce_ep<4><<<(N * C + 255) / 256, 256, 0, stream>>>(P, gb[lyr], masks, hout16[lyr], N, C);
            }
            hin16 = hout16[lyr];
        } else {
            final5_kernel<<<(N + 3) / 4, 256, 0, stream>>>(g, wstack, gb[4], masks, x,
                                                           (float*)d_out, N, KA);
        }
    }
}

// Round 16
// 699.390 us; speedup vs baseline: 1.2900x; 1.1008x over previous
//
#include <hip/hip_runtime.h>
#include <hip/hip_fp16.h>
#include <math.h>

// ---------------------------------------------------------------------------
// NetGlobGATFix. R16: 4-deep load pipelining in the edge loops.
//   - gat_gather / attn_kernel: edge loop unrolled x4 with gathers hoisted
//     (4 outstanding global loads instead of 1 -> hides ~200cyc L2 latency).
//     Accumulation order unchanged (bit-identical numerics).
//   - Everything else identical to R15 (770us).
// ---------------------------------------------------------------------------

#define DEVFN static __device__ __forceinline__

typedef __attribute__((ext_vector_type(8))) _Float16 half8;
typedef __attribute__((ext_vector_type(4))) float f32x4;

DEVFN float selu_f(float v) {
    const float scale = 1.0507009873554805f;
    const float alpha = 1.6732632423543772f;
    return v > 0.f ? scale * v : scale * alpha * (expf(v) - 1.f);
}

DEVFN float lrelu02(float v) { return v > 0.f ? v : 0.2f * v; }

// ---------------- CNN (padded 66x66 layout) ----------------
#define PST 66
#define PSZ (66 * 66)

__global__ void pad_input(const float* __restrict__ cf, float* __restrict__ out) {
    int t = blockIdx.x * blockDim.x + threadIdx.x;
    if (t >= 4 * 4096) return;
    int c = t >> 12, pix = t & 4095;
    int y = pix >> 6, x = pix & 63;
    out[c * PSZ + (y + 1) * PST + (x + 1)] = cf[t];
}

template <int CIN>
__global__ __launch_bounds__(256) void conv3x3_pad(const float* __restrict__ in,
                                                   const float* __restrict__ w,
                                                   const float* __restrict__ b,
                                                   float* __restrict__ out) {
    int x  = threadIdx.x & 63;
    int yg = threadIdx.x >> 6;
    int y0 = blockIdx.x * 16 + yg * 4;
    int co = blockIdx.y;
    float bv = b[co];
    float acc[4] = {bv, bv, bv, bv};
    const float* wp = w + (size_t)co * CIN * 9;
#pragma unroll 4
    for (int ci = 0; ci < CIN; ++ci) {
        const float* ip = in + ci * PSZ + y0 * PST + x;
        float wr[9];
#pragma unroll
        for (int j = 0; j < 9; ++j) wr[j] = wp[ci * 9 + j];
        float r[6][3];
#pragma unroll
        for (int rr = 0; rr < 6; ++rr) {
            r[rr][0] = ip[rr * PST + 0];
            r[rr][1] = ip[rr * PST + 1];
            r[rr][2] = ip[rr * PST + 2];
        }
#pragma unroll
        for (int v = 0; v < 4; ++v)
#pragma unroll
            for (int ky = 0; ky < 3; ++ky)
#pragma unroll
                for (int kx = 0; kx < 3; ++kx)
                    acc[v] += wr[ky * 3 + kx] * r[v + ky][kx];
    }
#pragma unroll
    for (int v = 0; v < 4; ++v)
        out[(size_t)co * PSZ + (y0 + v + 1) * PST + (x + 1)] = selu_f(acc[v]);
}

__global__ void avgpool_c(const float* __restrict__ in, float* __restrict__ gfeat) {
    int c = blockIdx.x;            // 24 blocks
    int t = threadIdx.x;           // 256 threads
    float s = 0.f;
    for (int i = t; i < 4096; i += 256) {
        int y = i >> 6, x = i & 63;
        s += in[c * PSZ + (y + 1) * PST + (x + 1)];
    }
#pragma unroll
    for (int off = 32; off >= 1; off >>= 1) s += __shfl_xor(s, off);
    __shared__ float red[4];
    int wave = t >> 6, lane = t & 63;
    if (lane == 0) red[wave] = s;
    __syncthreads();
    if (t == 0) gfeat[c] = (red[0] + red[1] + red[2] + red[3]) * (1.f / 4096.f);
}

// ---------------- node feature init (padded to 48 ch, fp16) + masks ---------
__global__ void build_h0(const float* __restrict__ x, const float* __restrict__ gfeat,
                         __half* __restrict__ h0f, unsigned* __restrict__ masks, int N) {
    int n = blockIdx.x * blockDim.x + threadIdx.x;
    if (n >= N) return;
    float x0 = x[n * 10 + 0], x1 = x[n * 10 + 1];
    unsigned mk = (x0 == 1.f ? 1u : 0u) | (x0 == 0.f ? 2u : 0u) |
                  (x1 == 0.f ? 4u : 0u) | (x1 == 1.f ? 8u : 0u);
    masks[n] = mk;
    __half* hq = h0f + (size_t)n * 48;
#pragma unroll
    for (int j = 0; j < 48; ++j) {
        float v = (j < 24) ? gfeat[j] : (j < 34 ? x[n * 10 + (j - 24)] : 0.f);
        hq[j] = __float2half(v);
    }
}

// ---------------- CSR build (parallel scan) ----------------
__global__ void count_dst(const int* __restrict__ ei, int* __restrict__ cnt, int E, int N) {
    int t = blockIdx.x * blockDim.x + threadIdx.x;
    if (t >= E + N) return;
    int dst = (t < E) ? ei[E + t] : (t - E);
    atomicAdd(&cnt[dst], 1);
}

__global__ void scan_blocks(const int* __restrict__ cnt, int* __restrict__ pref,
                            int* __restrict__ bsums, int n) {
    __shared__ int sdata[256];
    int i = blockIdx.x * 256 + threadIdx.x;
    int v = (i < n) ? cnt[i] : 0;
    sdata[threadIdx.x] = v;
    __syncthreads();
    for (int off = 1; off < 256; off <<= 1) {
        int tmp = (threadIdx.x >= off) ? sdata[threadIdx.x - off] : 0;
        __syncthreads();
        sdata[threadIdx.x] += tmp;
        __syncthreads();
    }
    if (i < n) pref[i] = sdata[threadIdx.x] - v;
    if (threadIdx.x == 255) bsums[blockIdx.x] = sdata[255];
}

__global__ void scan_sums(int* __restrict__ bsums, int nb) {
    int tid = threadIdx.x;                 // 64
    int orig = (tid < nb) ? bsums[tid] : 0;
    int v = orig;
#pragma unroll
    for (int off = 1; off < 64; off <<= 1) {
        int u = __shfl_up(v, off);
        if (tid >= off) v += u;
    }
    if (tid < nb) bsums[tid] = v - orig;
}

__global__ void scan_apply(const int* __restrict__ pref, const int* __restrict__ bsums,
                           int* __restrict__ indptr, int* __restrict__ cursor,
                           int n, int total) {
    int i = blockIdx.x * 256 + threadIdx.x;
    if (i == 0) indptr[n] = total;
    if (i >= n) return;
    int e = bsums[blockIdx.x] + pref[i];
    indptr[i] = e;
    cursor[i] = e;
}

__global__ void scatter_edges(const int* __restrict__ ei, int* __restrict__ cursor,
                              int* __restrict__ col, int E, int N) {
    int t = blockIdx.x * blockDim.x + threadIdx.x;
    if (t >= E + N) return;
    int src, dst;
    if (t < E) { src = ei[t]; dst = ei[E + t]; }
    else       { src = dst = t - E; }
    int pos = atomicAdd(&cursor[dst], 1);
    col[pos] = src;
}

// ---------------- fused weight prep (coalesced W reads) ---------------------
__global__ void prep_layer(const float* __restrict__ W, const float* __restrict__ as,
                           const float* __restrict__ ad,
                           unsigned short* __restrict__ bhi,
                           float* __restrict__ wstack, float* __restrict__ wesed,
                           int K, int Kp, int H, int C) {
    int KA = H * Kp;
    int H2 = 2 * H;
    int HC = H * C;
    int nwtb = (C > 2) ? Kp * HC : 0;
    int nws  = (C == 2) ? KA * 2 : 0;
    int t = blockIdx.x * blockDim.x + threadIdx.x;
    if (t < nwtb) {
        int k = t / HC, rem = t - k * HC;
        int h = rem / C, m = rem - h * C;
        float v = (k < K) ? W[(size_t)k * HC + rem] : 0.f;   // coalesced read
        bhi[(size_t)m * KA + h * Kp + k] = __half_as_ushort(__float2half(v));
    } else if (t < nwtb + nws) {
        int u = t - nwtb;
        int c = u & 1, r = u >> 1;           // r = h*Kp + k
        int h = r / Kp, k = r - h * Kp;
        wstack[u] = (k < K) ? W[(size_t)k * HC + h * C + c] : 0.f;
    } else if (t < nwtb + nws + Kp * H2) {
        int u = t - nwtb - nws;
        int k = u / H2, o = u - k * H2;
        float s = 0.f;
        if (k < K) {
            int h = (o < H) ? o : o - H;
            const float* av = ((o < H) ? as : ad) + h * C;
            const float* wp = W + (size_t)k * HC + h * C;
            for (int c = 0; c < C; ++c) s += wp[c] * av[c];
        }
        wesed[u] = s;
    }
}

// ---------------- es/ed: esed[n, o] = hin16[n,:] @ wesed[:,o], o < 2H -------
__global__ void esed_kernel(const __half* __restrict__ hin, const float* __restrict__ wesed,
                            float* __restrict__ esed, int N, int Kp, int H2) {
    int t = blockIdx.x * blockDim.x + threadIdx.x;
    if (t >= N * H2) return;
    int n = t / H2, o = t - n * H2;
    const __half2* hp = (const __half2*)(hin + (size_t)n * Kp);
    float s = 0.f;
    for (int k2 = 0; k2 < Kp / 2; ++k2) {
        float2 f = __half22float2(hp[k2]);
        s += f.x * wesed[(2 * k2) * H2 + o] + f.y * wesed[(2 * k2 + 1) * H2 + o];
    }
    esed[t] = s;
}

// -------- attention: single pass, 4-deep gather pipeline --------------------
__global__ void attn_kernel(const float* __restrict__ esed,
                            const int* __restrict__ indptr, const int* __restrict__ col,
                            float* __restrict__ palpha, float* __restrict__ zinv,
                            int N, int H) {
    int t = blockIdx.x * blockDim.x + threadIdx.x;
    if (t >= N * H) return;
    int n = t / H, h = t - n * H;
    int H2 = 2 * H;
    float edv = esed[n * H2 + H + h];
    int beg = indptr[n], end = indptr[n + 1];
    float z = 0.f;
    int i = beg;
    for (; i + 3 < end; i += 4) {
        int s0 = col[i], s1 = col[i + 1], s2 = col[i + 2], s3 = col[i + 3];
        float e0 = esed[s0 * H2 + h];
        float e1 = esed[s1 * H2 + h];
        float e2 = esed[s2 * H2 + h];
        float e3 = esed[s3 * H2 + h];
        float p0 = expf(lrelu02(e0 + edv));
        float p1 = expf(lrelu02(e1 + edv));
        float p2 = expf(lrelu02(e2 + edv));
        float p3 = expf(lrelu02(e3 + edv));
        palpha[(size_t)(i + 0) * H + h] = p0;
        palpha[(size_t)(i + 1) * H + h] = p1;
        palpha[(size_t)(i + 2) * H + h] = p2;
        palpha[(size_t)(i + 3) * H + h] = p3;
        z += p0; z += p1; z += p2; z += p3;
    }
    for (; i < end; ++i) {
        float e = lrelu02(esed[col[i] * H2 + h] + edv);
        float p = expf(e);
        palpha[(size_t)i * H + h] = p;
        z += p;
    }
    zinv[t] = (1.f / H) / (z + 1e-16f);
}

// -------- gather: 4-deep hin pipeline ---------------------------------------
template <int H, int KP, int NPB>
__global__ __launch_bounds__(NPB * KP / 2) void gat_gather(
        const __half* __restrict__ hinf, const float* __restrict__ palpha,
        const float* __restrict__ zinv, const int* __restrict__ indptr,
        const int* __restrict__ col, __half* __restrict__ g, int N) {
    const int TPN = KP / 2;
    int sub = threadIdx.x / TPN;
    int j   = threadIdx.x % TPN;
    int n = blockIdx.x * NPB + sub;
    if (n >= N) return;
    int c0 = j * 2;
    float acc[H][2];
#pragma unroll
    for (int h = 0; h < H; ++h) { acc[h][0] = 0.f; acc[h][1] = 0.f; }
    int beg = indptr[n], end = indptr[n + 1];
    int i = beg;
    for (; i + 3 < end; i += 4) {
        int s0 = col[i], s1 = col[i + 1], s2 = col[i + 2], s3 = col[i + 3];
        __half2 hv0 = *(const __half2*)(hinf + (size_t)s0 * KP + c0);
        __half2 hv1 = *(const __half2*)(hinf + (size_t)s1 * KP + c0);
        __half2 hv2 = *(const __half2*)(hinf + (size_t)s2 * KP + c0);
        __half2 hv3 = *(const __half2*)(hinf + (size_t)s3 * KP + c0);
        float2 fv[4] = {__half22float2(hv0), __half22float2(hv1),
                        __half22float2(hv2), __half22float2(hv3)};
#pragma unroll
        for (int e = 0; e < 4; ++e) {
            const float2* ap = (const float2*)(palpha + (size_t)(i + e) * H);
            float2 f = fv[e];
#pragma unroll
            for (int h2 = 0; h2 < H / 2; ++h2) {
                float2 aa = ap[h2];
                acc[2 * h2 + 0][0] += aa.x * f.x;
                acc[2 * h2 + 0][1] += aa.x * f.y;
                acc[2 * h2 + 1][0] += aa.y * f.x;
                acc[2 * h2 + 1][1] += aa.y * f.y;
            }
        }
    }
    for (; i < end; ++i) {
        int src = col[i];
        __half2 hv = *(const __half2*)(hinf + (size_t)src * KP + c0);
        float2 f = __half22float2(hv);
        const float2* ap = (const float2*)(palpha + (size_t)i * H);
#pragma unroll
        for (int h2 = 0; h2 < H / 2; ++h2) {
            float2 aa = ap[h2];
            acc[2 * h2 + 0][0] += aa.x * f.x;
            acc[2 * h2 + 0][1] += aa.x * f.y;
            acc[2 * h2 + 1][0] += aa.y * f.x;
            acc[2 * h2 + 1][1] += aa.y * f.y;
        }
    }
    __half* gp = g + (size_t)n * (H * KP) + c0;
#pragma unroll
    for (int h = 0; h < H; ++h) {
        float zf = zinv[n * H + h];
        *(__half2*)(gp + h * KP) = __floats2half2_rn(acc[h][0] * zf, acc[h][1] * zf);
    }
}

// ---------------- multi-row-tile split-K f16 MFMA GEMM ----------------------
template <int RT, int SPLIT>
__global__ __launch_bounds__(64) void gemm_mr(const __half* __restrict__ A,
                                              const unsigned short* __restrict__ Bhi,
                                              const float* __restrict__ bias,
                                              const unsigned* __restrict__ masks,
                                              float* __restrict__ P,
                                              __half* __restrict__ O16,
                                              int N, int K, int M) {
    int lane = threadIdx.x;
    int ln16 = lane & 15;
    int q    = lane >> 4;                 // 0..3 (k-octet)
    int row0 = blockIdx.x * (16 * RT);
    int col0 = blockIdx.y * 64;
    int kb   = (K / SPLIT) * blockIdx.z;
    int ke   = kb + K / SPLIT;

    const __half* ap = A + (size_t)(row0 + ln16) * K + q * 8;
    const unsigned short* bhp = Bhi + (size_t)(col0 + ln16) * K + q * 8;
    const size_t cstep = (size_t)16 * K;

    f32x4 acc[RT][4];
#pragma unroll
    for (int rt = 0; rt < RT; ++rt)
#pragma unroll
        for (int j = 0; j < 4; ++j) acc[rt][j] = (f32x4){0.f, 0.f, 0.f, 0.f};

#pragma unroll 2
    for (int kc = kb; kc < ke; kc += 32) {
        half8 bh[4];
#pragma unroll
        for (int j = 0; j < 4; ++j)
            bh[j] = *(const half8*)(bhp + (size_t)j * cstep + kc);
        half8 a[RT];
#pragma unroll
        for (int rt = 0; rt < RT; ++rt)
            a[rt] = *(const half8*)(ap + (size_t)rt * cstep + kc);
#pragma unroll
        for (int rt = 0; rt < RT; ++rt) {
#pragma unroll
            for (int j = 0; j < 4; ++j)
                acc[rt][j] = __builtin_amdgcn_mfma_f32_16x16x32_f16(a[rt], bh[j], acc[rt][j], 0, 0, 0);
        }
    }

    // C/D layout: col = lane&15, row = (lane>>4)*4 + reg
    if (SPLIT == 1) {
#pragma unroll
        for (int rt = 0; rt < RT; ++rt) {
#pragma unroll
            for (int j = 0; j < 4; ++j) {
                int cc = col0 + j * 16 + ln16;
                float bv = bias[cc];
#pragma unroll
                for (int r = 0; r < 4; ++r) {
                    int rr = row0 + rt * 16 + q * 4 + r;
                    if (rr >= N) continue;
                    float v = selu_f(acc[rt][j][r] + bv);
                    if (cc < 2) {
                        unsigned mk = masks[rr];
                        if (cc == 0) { if (mk & 2u) v = 0.f; else if (mk & 1u) v = 1.f; }
                        else         { if (mk & 8u) v = 1.f; else if (mk & 4u) v = 0.f; }
                    }
                    O16[(size_t)rr * M + cc] = __float2half(v);
                }
            }
        }
    } else {
        float* Pz = P + (size_t)blockIdx.z * N * M;
#pragma unroll
        for (int rt = 0; rt < RT; ++rt) {
#pragma unroll
            for (int j = 0; j < 4; ++j) {
                int cc = col0 + j * 16 + ln16;
#pragma unroll
                for (int r = 0; r < 4; ++r) {
                    int rr = row0 + rt * 16 + q * 4 + r;
                    if (rr >= N) continue;
                    Pz[(size_t)rr * M + cc] = acc[rt][j][r];
                }
            }
        }
    }
}

// ---------------- reduce partials + bias/selu/boundary -> fp16 --------------
template <int SPLIT>
__global__ __launch_bounds__(256) void reduce_ep(const float* __restrict__ P,
                                                 const float* __restrict__ bias,
                                                 const unsigned* __restrict__ masks,
                                                 __half* __restrict__ O16,
                                                 int N, int M) {
    int t = blockIdx.x * 256 + threadIdx.x;
    if (t >= N * M) return;
    int n = t / M, c = t - n * M;
    float v = 0.f;
#pragma unroll
    for (int s = 0; s < SPLIT; ++s) v += P[(size_t)s * N * M + t];
    v = selu_f(v + bias[c]);
    if (c < 2) {
        unsigned mk = masks[n];
        if (c == 0) { if (mk & 2u) v = 0.f; else if (mk & 1u) v = 1.f; }
        else        { if (mk & 8u) v = 1.f; else if (mk & 4u) v = 0.f; }
    }
    O16[t] = __float2half(v);
}

// ---------------- final layer (C=2): out = bfix(x + selu(g @ W5s + b5)) -----
__global__ __launch_bounds__(256) void final5_kernel(const __half* __restrict__ g,
                                                     const float* __restrict__ W5,
                                                     const float* __restrict__ b5,
                                                     const unsigned* __restrict__ masks,
                                                     const float* __restrict__ x,
                                                     float* __restrict__ out,
                                                     int N, int KA) {
    int wave = threadIdx.x >> 6, lane = threadIdx.x & 63;
    int n = blockIdx.x * 4 + wave;
    if (n >= N) return;
    float a0 = 0.f, a1 = 0.f;
    const __half* gp = g + (size_t)n * KA;
    for (int k = lane * 2; k < KA; k += 128) {
        float2 f = __half22float2(*(const __half2*)(gp + k));
        float4 w = *(const float4*)(W5 + (size_t)k * 2);
        a0 += f.x * w.x + f.y * w.z;
        a1 += f.x * w.y + f.y * w.w;
    }
#pragma unroll
    for (int off = 32; off >= 1; off >>= 1) {
        a0 += __shfl_xor(a0, off);
        a1 += __shfl_xor(a1, off);
    }
    if (lane == 0) {
        unsigned mk = masks[n];
        float v0 = x[n * 10 + 0] + selu_f(a0 + b5[0]);
        float v1 = x[n * 10 + 1] + selu_f(a1 + b5[1]);
        if (mk & 2u) v0 = 0.f; else if (mk & 1u) v0 = 1.f;
        if (mk & 8u) v1 = 1.f; else if (mk & 4u) v1 = 0.f;
        out[n * 2 + 0] = v0;
        out[n * 2 + 1] = v1;
    }
}

// ---------------------------------------------------------------------------
extern "C" void kernel_launch(void* const* d_in, const int* in_sizes, int n_in,
                              void* d_out, int out_size, void* d_ws, size_t ws_size,
                              hipStream_t stream) {
    const float* x   = (const float*)d_in[0];
    const int*   ei  = (const int*)d_in[1];
    const float* cf  = (const float*)d_in[2];
    const float* cw[4] = {(const float*)d_in[3], (const float*)d_in[5],
                          (const float*)d_in[7], (const float*)d_in[9]};
    const float* cb[4] = {(const float*)d_in[4], (const float*)d_in[6],
                          (const float*)d_in[8], (const float*)d_in[10]};
    const float* gw[5], *gas[5], *gad[5], *gb[5];
    for (int i = 0; i < 5; ++i) {
        gw[i]  = (const float*)d_in[11 + 4 * i];
        gas[i] = (const float*)d_in[12 + 4 * i];
        gad[i] = (const float*)d_in[13 + 4 * i];
        gb[i]  = (const float*)d_in[14 + 4 * i];
    }
    const int N = in_sizes[0] / 10;        // 10000
    const int E = in_sizes[1] / 2;         // 160000
    const int EN = E + N;
    const int NB = (N + 255) / 256;        // scan blocks (40)

    // ---- workspace carve-up ----
    char* base = (char*)d_ws;
    size_t off = 0;
    auto alloc = [&](size_t bytes) -> char* {
        char* p = base + off;
        off = (off + bytes + 255) & ~(size_t)255;
        return p;
    };
    float* cfp   = (float*)alloc((size_t)4 * PSZ * 4);
    float* c1p   = (float*)alloc((size_t)16 * PSZ * 4);
    float* c2p   = (float*)alloc((size_t)32 * PSZ * 4);
    float* c3p   = (float*)alloc((size_t)64 * PSZ * 4);
    float* c4p   = (float*)alloc((size_t)24 * PSZ * 4);
    float* gfeat = (float*)alloc(24 * 4);
    __half* hA16 = (__half*)alloc((size_t)N * 256 * 2);
    __half* hB16 = (__half*)alloc((size_t)N * 256 * 2);
    __half* g    = (__half*)alloc((size_t)N * 2048 * 2);
    float* P     = (float*)alloc((size_t)4 * N * 256 * 4);   // 41 MB partials
    float* esed  = (float*)alloc((size_t)N * 32 * 4);
    float* zinv  = (float*)alloc((size_t)N * 16 * 4);
    float* palpha = (float*)alloc((size_t)EN * 16 * 4);      // fp32 numerators
    float* wesed = (float*)alloc(256 * 32 * 4);
    float* wstack= (float*)alloc((size_t)2048 * 2 * 4);
    unsigned short* bt_hi = (unsigned short*)alloc((size_t)524288 * 2);
    unsigned* masks = (unsigned*)alloc((size_t)N * 4);
    int* cnt    = (int*)alloc((size_t)N * 4);
    int* pref   = (int*)alloc((size_t)N * 4);
    int* bsums  = (int*)alloc(64 * 4);
    int* indptr = (int*)alloc((size_t)(N + 1) * 4);
    int* cursor = (int*)alloc((size_t)N * 4);
    int* col    = (int*)alloc((size_t)EN * 4);
    (void)ws_size; // ~119 MB

    // ---- CNN (padded layout; single memset zeroes all borders) ----
    hipMemsetAsync(cfp, 0, (size_t)140 * PSZ * 4, stream);
    pad_input<<<(4 * 4096 + 255) / 256, 256, 0, stream>>>(cf, cfp);
    conv3x3_pad<4><<<dim3(4, 16), 256, 0, stream>>>(cfp, cw[0], cb[0], c1p);
    conv3x3_pad<16><<<dim3(4, 32), 256, 0, stream>>>(c1p, cw[1], cb[1], c2p);
    conv3x3_pad<32><<<dim3(4, 64), 256, 0, stream>>>(c2p, cw[2], cb[2], c3p);
    conv3x3_pad<64><<<dim3(4, 24), 256, 0, stream>>>(c3p, cw[3], cb[3], c4p);
    avgpool_c<<<24, 256, 0, stream>>>(c4p, gfeat);

    // ---- h0 (padded to 48, fp16) + masks ----
    build_h0<<<(N + 255) / 256, 256, 0, stream>>>(x, gfeat, hA16, masks, N);

    // ---- CSR by dst (incl self loops), parallel scan ----
    hipMemsetAsync(cnt, 0, (size_t)N * 4, stream);
    count_dst<<<(EN + 255) / 256, 256, 0, stream>>>(ei, cnt, E, N);
    scan_blocks<<<NB, 256, 0, stream>>>(cnt, pref, bsums, N);
    scan_sums<<<1, 64, 0, stream>>>(bsums, NB);
    scan_apply<<<NB, 256, 0, stream>>>(pref, bsums, indptr, cursor, N, EN);
    scatter_edges<<<(EN + 255) / 256, 256, 0, stream>>>(ei, cursor, col, E, N);

    // ---- GAT layers ----
    const int Ko[5] = {34, 64, 128, 256, 128};   // true input dims
    const int Kp[5] = {48, 64, 128, 256, 128};   // padded
    const int Hs[5] = {8, 16, 8, 8, 16};
    const int Cs[5] = {64, 128, 256, 128, 2};

    const __half* hin16 = hA16;
    __half* hout16[4]  = {hB16, hA16, hB16, hA16};

    for (int lyr = 0; lyr < 5; ++lyr) {
        int K = Ko[lyr], KP = Kp[lyr], H = Hs[lyr], C = Cs[lyr];
        int KA = H * KP;
        int nprep = ((C > 2) ? KP * H * C : KA * 2) + KP * 2 * H;
        prep_layer<<<(nprep + 255) / 256, 256, 0, stream>>>(gw[lyr], gas[lyr], gad[lyr],
                                                            bt_hi, wstack, wesed,
                                                            K, KP, H, C);
        esed_kernel<<<(N * 2 * H + 255) / 256, 256, 0, stream>>>(hin16, wesed, esed, N, KP, 2 * H);
        attn_kernel<<<(N * H + 255) / 256, 256, 0, stream>>>(esed, indptr, col,
                                                             palpha, zinv, N, H);
        if (lyr == 0)
            gat_gather<8, 48, 10><<<(N + 9) / 10, 240, 0, stream>>>(hin16, palpha, zinv, indptr, col, g, N);
        else if (lyr == 1)
            gat_gather<16, 64, 8><<<(N + 7) / 8, 256, 0, stream>>>(hin16, palpha, zinv, indptr, col, g, N);
        else if (lyr == 2)
            gat_gather<8, 128, 4><<<(N + 3) / 4, 256, 0, stream>>>(hin16, palpha, zinv, indptr, col, g, N);
        else if (lyr == 3)
            gat_gather<8, 256, 2><<<(N + 1) / 2, 256, 0, stream>>>(hin16, palpha, zinv, indptr, col, g, N);
        else
            gat_gather<16, 128, 4><<<(N + 3) / 4, 256, 0, stream>>>(hin16, palpha, zinv, indptr, col, g, N);

        if (lyr < 4) {
            if (lyr == 0) {            // KA=384, C=64: RT=2, SPLIT=4
                dim3 gg((N + 31) / 32, C / 64, 4);
                gemm_mr<2, 4><<<gg, 64, 0, stream>>>(g, bt_hi, gb[lyr], masks, P, hout16[lyr], N, KA, C);
                reduce_ep<4><<<(N * C + 255) / 256, 256, 0, stream>>>(P, gb[lyr], masks, hout16[lyr], N, C);
            } else if (lyr == 2) {     // KA=1024, C=256: RT=4, SPLIT=4
                dim3 gg((N + 63) / 64, C / 64, 4);
                gemm_mr<4, 4><<<gg, 64, 0, stream>>>(g, bt_hi, gb[lyr], masks, P, hout16[lyr], N, KA, C);
                reduce_ep<4><<<(N * C + 255) / 256, 256, 0, stream>>>(P, gb[lyr], masks, hout16[lyr], N, C);
            } else {                   // KA=1024/2048, C=128: RT=2, SPLIT=4
                dim3 gg((N + 31) / 32, C / 64, 4);
                gemm_mr<2, 4><<<gg, 64, 0, stream>>>(g, bt_hi, gb[lyr], masks, P, hout16[lyr], N, KA, C);
                reduce_ep<4><<<(N * C + 255) / 256, 256, 0, stream>>>(P, gb[lyr], masks, hout16[lyr], N, C);
            }
            hin16 = hout16[lyr];
        } else {
            final5_kernel<<<(N + 3) / 4, 256, 0, stream>>>(g, wstack, gb[4], masks, x,
                                                           (float*)d_out, N, KA);
        }
    }
}